// Round 16
// baseline (1391.570 us; speedup 1.0000x reference)
//
#include <hip/hip_runtime.h>
#include <math.h>

#define H 1024
#define BATCH 512
#define KSTEPS 96
#define KH ((long)KSTEPS * H)

typedef __attribute__((ext_vector_type(8))) short short8;
typedef __attribute__((ext_vector_type(16))) float f32x16;

__device__ __forceinline__ unsigned short f2bf(float x) {
    union { float f; unsigned int u; } v; v.f = x;
    unsigned int r = v.u + 0x7fffu + ((v.u >> 16) & 1u);
    return (unsigned short)(r >> 16);
}
__device__ __forceinline__ float bf2f(unsigned short h) {
    union { unsigned int u; float f; } v; v.u = ((unsigned int)h) << 16;
    return v.f;
}

// fast saturating gate math (v_exp_f32; NaN-free at +-inf)
__device__ __forceinline__ float fsig(float x)  { return 1.f / (1.f + __expf(-x)); }
__device__ __forceinline__ float ftanh(float x) { return 1.f - 2.f / (1.f + __expf(2.f * x)); }

// async global->LDS 16B/lane; dst wave-uniform base (HW adds lane*16)
__device__ __forceinline__ void glds16(const void* g, void* l) {
    __builtin_amdgcn_global_load_lds(
        (const __attribute__((address_space(1))) void*)g,
        (__attribute__((address_space(3))) void*)l, 16, 0, 0);
}
#define MEMFENCE asm volatile("" ::: "memory")

// ---------------------------------------------------------------------------
// Workspace layouts (32x32x16 MFMA fragment order):
//  blob0/blob1: [32 tc][64 by][2 s][2 jt][2 kg][64 l][8 e] bf16   (W hi+lo)
//  bcJ: [4096] f32 J-interleaved fused biases
//  hTa/hTb: [32 tc][4 bx][2 s][2 mh][2 mt][2 kg][64 l][8 e] bf16 — s=0 only
//  bar: [512] u32 — arrive[0..255] (one slot per block), go at bar[384]
// ---------------------------------------------------------------------------

__global__ void prep_w(const float* __restrict__ wih,
                       const float* __restrict__ whh,
                       unsigned short* __restrict__ blob0,
                       unsigned short* __restrict__ blob1)
{
    const unsigned int f = blockIdx.x * 256 + threadIdx.x;  // 0..8388607
    const int e  = f & 7;
    const int l  = (f >> 3) & 63;
    const int kg = (f >> 9) & 1;
    const int jt = (f >> 10) & 1;
    const int s  = (f >> 11) & 1;
    const int by = (f >> 12) & 63;
    const int tc = (f >> 18) & 31;
    const int b  = blockIdx.y;      // blob select

    const int J = by * 64 + jt * 32 + (l & 31);
    const int g = J & 3;
    const long j = J >> 2;
    const long k = (long)tc * 32 + kg * 16 + (l >> 5) * 8 + e;

    float v = 0.f;
    if (b == 1) {
        if (g == 0)      v = wih[j*1024 + k]           + whh[j*1024 + k];
        else if (g == 1) v = wih[(1024+j)*1024 + k]    + whh[(1024+j)*1024 + k];
        else if (g == 2) v = wih[(2048+j)*1024 + k];
        else             v = whh[(2048+j)*1024 + k];
    } else {
        if (g == 0)      v = whh[j*1024 + k];
        else if (g == 1) v = whh[(1024+j)*1024 + k];
        else if (g == 2) v = 0.f;
        else             v = whh[(2048+j)*1024 + k];
    }
    const unsigned short hi = f2bf(v);
    unsigned short* blob = (b == 0) ? blob0 : blob1;
    blob[f] = (s == 0) ? hi : f2bf(v - bf2f(hi));
}

__global__ void prep_bcJ(const float* __restrict__ bih,
                         const float* __restrict__ bhh,
                         float* __restrict__ bcJ,
                         unsigned int* __restrict__ bar)
{
    const int J = blockIdx.x * 256 + threadIdx.x;   // 0..4095
    const int g = J & 3;
    const int j = J >> 2;
    float v;
    if (g == 0)      v = bih[j]        + bhh[j];
    else if (g == 1) v = bih[1024 + j] + bhh[1024 + j];
    else if (g == 2) v = bih[2048 + j];
    else             v = bhh[2048 + j];
    bcJ[J] = v;
    if (blockIdx.x == 0) {                 // zero barrier state (512 u32)
        bar[threadIdx.x]       = 0u;
        bar[256 + threadIdx.x] = 0u;
    }
}

// c [512][1024] fp32 -> hT fragment layout, hi (s=0) only
__global__ void prep_h0(const float* __restrict__ cin,
                        unsigned short* __restrict__ hT)
{
    const unsigned int f = blockIdx.x * 256 + threadIdx.x;   // 0..524287
    const int e  = f & 7;
    const int l  = (f >> 3) & 63;
    const int kg = (f >> 9) & 1;
    const int mt = (f >> 10) & 1;
    const int mh = (f >> 11) & 1;
    const int bx = (f >> 12) & 3;
    const int tc = (f >> 14) & 31;

    const long m = bx * 128 + mh * 64 + mt * 32 + (l & 31);
    const long k = (long)tc * 32 + kg * 16 + (l >> 5) * 8 + e;

    const long addr = (long)tc*32768 + bx*8192 /* s=0 */ + mh*2048 + mt*1024
                    + kg*512 + l*8 + e;
    hT[addr] = f2bf(cin[m * 1024 + k]);
}

// ---------------------------------------------------------------------------
// Persistent GRU: all 96 steps in ONE cooperative launch.
// Grid 256 (1/CU), 512 threads (8 waves). 2-PRODUCT split:
//   W·h ≈ (W_hi + W_lo)·h_hi. 16 MFMA/chunk/wave. r14 K-loop chassis.
// r16: contention-free split barrier:
//   - arrive: each block stores k to its OWN slot (sc0 sc1, parallel).
//   - master (block 0, wave 0) polls all 256 slots, releases go=k.
//   - leaders poll go. No atomics, no same-line contention.
//   W(0),W(1) staged via glds16 UNDER the barrier wait (no h dependency).
// Coherence: hT written sc0 sc1 write-through, read sc0 sc1 system-scope;
// out nontemporal; exact h_prev carried in hp[] registers.
// ---------------------------------------------------------------------------
__global__ __launch_bounds__(512) void gru_all(
    const unsigned short* __restrict__ blob0,
    const unsigned short* __restrict__ blob1,
    unsigned short* __restrict__ hTa,
    unsigned short* __restrict__ hTb,
    const float* __restrict__ cin,
    const float* __restrict__ bcJ,
    float* __restrict__ out,
    unsigned int* bar)
{
    __shared__ __attribute__((aligned(16))) char smem[131072]; // W: 4gk x 3 x 8KB; D reuse 128KB

    const int tid  = threadIdx.x;
    const int lane = tid & 63;
    const int wv   = tid >> 6;        // 0..7
    const int gk   = wv >> 1;         // K-quarter 0..3
    const int mh   = wv & 1;          // m-half within 128

    const int id   = blockIdx.x;
    const int grp  = id & 7;
    const int slot = id >> 3;
    const int by   = grp * 8 + (slot & 7);   // 0..63  (J tile)
    const int bx   = slot >> 3;              // 0..3   (m tile)
    const long m0  = (long)bx * 128;

    const float bb0 = bcJ[by*64 + (lane & 31)];
    const float bb1 = bcJ[by*64 + 32 + (lane & 31)];

    // h_prev carried in registers: same (m,j) per thread every step
    float hp[4];
    #pragma unroll
    for (int it = 0; it < 4; ++it) {
        const int qi = it * 512 + tid;
        const int jl = qi & 15;
        const int m  = qi >> 4;
        hp[it] = cin[(m0 + m) * 1024 + (long)by * 16 + jl];
    }

    #pragma unroll 1
    for (int k = 0; k < KSTEPS; ++k) {
        const unsigned short* wbl = (k == 0) ? blob0 : blob1;
        const unsigned short* hTr = (k & 1) ? hTb : hTa;
        unsigned short*       hTw = (k & 1) ? hTa : hTb;
        float* outk = out + (long)k * H;

        const char* wsrc = (const char*)wbl + (long)by * 8192;   // + tc*524288
        const char* hsrc = (const char*)hTr + (long)bx * 16384;  // + tc*65536

        f32x16 acc[2][2];   // [mt][jt]
        {
            const float a0 = (gk == 0) ? bb0 : 0.f;
            const float a1 = (gk == 0) ? bb1 : 0.f;
            #pragma unroll
            for (int mt = 0; mt < 2; ++mt)
                #pragma unroll
                for (int r = 0; r < 16; ++r) { acc[mt][0][r] = a0; acc[mt][1][r] = a1; }
        }

        short8 A0[4], A1[4], A2[4];   // 3 rotating sets, [mt*2+kg], hi only

        auto loadA = [&](int c, short8* A) {
            const char* hs = hsrc + (long)(gk * 8 + c) * 65536;
            #pragma unroll
            for (int mt = 0; mt < 2; ++mt)
                #pragma unroll
                for (int kg = 0; kg < 2; ++kg) {
                    const void* p = hs + (long)(((mh*2+mt)*2)+kg)*1024 + lane*16;
                    asm volatile("global_load_dwordx4 %0, %1, off sc0 sc1"
                                 : "=v"(A[mt*2+kg]) : "v"(p) : "memory");
                }
        };
        auto stageW = [&](int c) {
            const char* ws = wsrc + (long)(gk * 8 + c) * 524288;
            char* dst = smem + gk * 24576 + (c % 3) * 8192;
            #pragma unroll
            for (int o = 0; o < 4; ++o)
                glds16(ws + (mh*4+o)*1024 + lane*16, dst + (mh*4+o)*1024);
        };
        auto compute = [&](const char* wb, const short8* A) {
            #pragma unroll
            for (int kg = 0; kg < 2; ++kg) {
                const short8 bh0 = *(const short8*)(wb + (0*4 + 0*2 + kg)*1024 + lane*16);
                const short8 bh1 = *(const short8*)(wb + (0*4 + 1*2 + kg)*1024 + lane*16);
                const short8 bl0 = *(const short8*)(wb + (1*4 + 0*2 + kg)*1024 + lane*16);
                const short8 bl1 = *(const short8*)(wb + (1*4 + 1*2 + kg)*1024 + lane*16);
                const short8 ah0 = A[0*2 + kg];
                const short8 ah1 = A[1*2 + kg];
                acc[0][0] = __builtin_amdgcn_mfma_f32_32x32x16_bf16(ah0, bh0, acc[0][0], 0, 0, 0);
                acc[0][1] = __builtin_amdgcn_mfma_f32_32x32x16_bf16(ah0, bh1, acc[0][1], 0, 0, 0);
                acc[1][0] = __builtin_amdgcn_mfma_f32_32x32x16_bf16(ah1, bh0, acc[1][0], 0, 0, 0);
                acc[1][1] = __builtin_amdgcn_mfma_f32_32x32x16_bf16(ah1, bh1, acc[1][1], 0, 0, 0);
                acc[0][0] = __builtin_amdgcn_mfma_f32_32x32x16_bf16(ah0, bl0, acc[0][0], 0, 0, 0);
                acc[0][1] = __builtin_amdgcn_mfma_f32_32x32x16_bf16(ah0, bl1, acc[0][1], 0, 0, 0);
                acc[1][0] = __builtin_amdgcn_mfma_f32_32x32x16_bf16(ah1, bl0, acc[1][0], 0, 0, 0);
                acc[1][1] = __builtin_amdgcn_mfma_f32_32x32x16_bf16(ah1, bl1, acc[1][1], 0, 0, 0);
            }
        };

        // ---- step boundary ----
        if (k > 0) __syncthreads();      // all waves done reading D (epilogue)

        // stage next W(0),W(1) under the barrier wait (no h dependency)
        stageW(0); MEMFENCE;
        stageW(1); MEMFENCE;

        if (k > 0) {
            // arrive: one plain system-scope store per block, zero contention
            if (tid == 0) {
                const unsigned kk = (unsigned)k;
                unsigned int* slotp = bar + id;
                asm volatile("global_store_dword %0, %1, off sc0 sc1"
                             :: "v"(slotp), "v"(kk) : "memory");
            }
            // master: block 0 wave 0 polls all 256 arrive slots (4 per lane)
            if (id == 0 && tid < 64) {
                #pragma unroll
                for (int s = 0; s < 4; ++s) {
                    unsigned int* sp = bar + (s * 64 + tid);
                    while (true) {
                        unsigned v;
                        asm volatile("global_load_dword %0, %1, off sc0 sc1\n\t"
                                     "s_waitcnt vmcnt(0)"
                                     : "=v"(v) : "v"(sp) : "memory");
                        if (v >= (unsigned)k) break;
                        __builtin_amdgcn_s_sleep(4);
                    }
                }
            }
            if (id == 0) {
                __syncthreads();
                if (tid == 0) {
                    const unsigned kk = (unsigned)k;
                    unsigned int* gp = bar + 384;
                    asm volatile("global_store_dword %0, %1, off sc0 sc1"
                                 :: "v"(gp), "v"(kk) : "memory");
                }
            } else if (tid == 0) {
                unsigned int* gp = bar + 384;
                while (true) {
                    unsigned v;
                    asm volatile("global_load_dword %0, %1, off sc0 sc1\n\t"
                                 "s_waitcnt vmcnt(0)"
                                 : "=v"(v) : "v"(gp) : "memory");
                    if (v >= (unsigned)k) break;
                    __builtin_amdgcn_s_sleep(4);
                }
            }
            __syncthreads();             // whole block released; hT globally ready
        }

        // ---- A prologue (h-dependent, after barrier) ----
        loadA(0, A0); MEMFENCE;
        loadA(1, A1); MEMFENCE;
        // FIFO: W0(4),W1(4),A0(4),A1(4); vmcnt(4) drains W0,W1,A0 — A1 flying
        asm volatile("s_waitcnt vmcnt(4)" ::: "memory");
        __builtin_amdgcn_sched_barrier(0);
        __builtin_amdgcn_s_barrier();

        // Per chunk c: issue A(c+2),W(c+2); compute(c); vmcnt(8) drains
        // A(c+1),W(c+1) (issued one full chunk earlier); barrier.
        #define CHUNK(c, Ac, An)                                               \
        {                                                                      \
            if ((c) <= 5) { loadA((c)+2, An); MEMFENCE;                        \
                            stageW((c)+2); MEMFENCE; }                         \
            __builtin_amdgcn_sched_barrier(0);                                 \
            __builtin_amdgcn_s_setprio(1);                                     \
            compute(smem + gk*24576 + ((c)%3)*8192, Ac);                       \
            __builtin_amdgcn_s_setprio(0);                                     \
            if ((c) <= 5)      asm volatile("s_waitcnt vmcnt(8)" ::: "memory");\
            else if ((c) == 6) asm volatile("s_waitcnt vmcnt(0)" ::: "memory");\
            __builtin_amdgcn_sched_barrier(0);                                 \
            __builtin_amdgcn_s_barrier();                                      \
        }
        CHUNK(0, A0, A2) CHUNK(1, A1, A0) CHUNK(2, A2, A1) CHUNK(3, A0, A2)
        CHUNK(4, A1, A0) CHUNK(5, A2, A1) CHUNK(6, A0, A2) CHUNK(7, A1, A0)
        #undef CHUNK

        __syncthreads();   // LDS reads done; smem becomes epilogue scratch

        // ---- epilogue: dump partials, 4-way reduce, gates ----
        float* D = (float*)smem;   // [4 gk][128 m][64 J]
        #pragma unroll
        for (int mt = 0; mt < 2; ++mt)
            #pragma unroll
            for (int jt = 0; jt < 2; ++jt)
                #pragma unroll
                for (int r = 0; r < 16; ++r) {
                    const int r32 = (r & 3) + 8 * (r >> 2) + 4 * (lane >> 5);
                    const int m  = mh * 64 + mt * 32 + r32;
                    const int J  = jt * 32 + (lane & 31);
                    D[(gk * 128 + m) * 64 + J] = acc[mt][jt][r];
                }
        __syncthreads();

        #pragma unroll
        for (int it = 0; it < 4; ++it) {
            const int qi = it * 512 + tid;     // 0..2047
            const int jl = qi & 15;
            const int m  = qi >> 4;            // 0..127
            const float4 s0 = *(const float4*)&D[(0*128 + m)*64 + 4*jl];
            const float4 s1 = *(const float4*)&D[(1*128 + m)*64 + 4*jl];
            const float4 s2 = *(const float4*)&D[(2*128 + m)*64 + 4*jl];
            const float4 s3 = *(const float4*)&D[(3*128 + m)*64 + 4*jl];
            const float gr = s0.x + s1.x + s2.x + s3.x;
            const float gz = s0.y + s1.y + s2.y + s3.y;
            const float gi = s0.z + s1.z + s2.z + s3.z;
            const float gh = s0.w + s1.w + s2.w + s3.w;

            const long mg = m0 + m;
            const long j  = (long)by * 16 + jl;

            const float rr = fsig(gr);
            const float zz = fsig(gz);
            const float nn = ftanh(fmaf(rr, gh, gi));
            const float o  = nn + zz * (hp[it] - nn);
            hp[it] = o;

            __builtin_nontemporal_store(o, &outk[mg * KH + j]);

            // hT writeback (hi only) — sc0 sc1 write-through
            const unsigned short hi = f2bf(o);
            const int kk  = (int)j;
            const int tc2 = kk >> 5;
            const int kg2 = (kk >> 4) & 1;
            const int lh  = (kk >> 3) & 1;
            const int e2  = kk & 7;
            const int mh2 = (m >> 6) & 1;
            const int mt2 = (m >> 5) & 1;
            const int row = m & 31;
            const long ub = (long)tc2*32768 + bx*8192 + mh2*2048 + mt2*1024
                          + kg2*512 + (lh*32 + row)*8 + e2;
            unsigned short* p0 = hTw + ub;
            asm volatile("global_store_short %0, %1, off sc0 sc1"
                         :: "v"(p0), "v"((unsigned)hi) : "memory");
        }
        asm volatile("s_waitcnt vmcnt(0)" ::: "memory");   // hT drained before arrive
    }
}

// ---------------------------------------------------------------------------
extern "C" void kernel_launch(void* const* d_in, const int* in_sizes, int n_in,
                              void* d_out, int out_size, void* d_ws, size_t ws_size,
                              hipStream_t stream)
{
    const float* c   = (const float*)d_in[0];
    // d_in[1] = K (fixed 96)
    const float* wih = (const float*)d_in[2];
    const float* whh = (const float*)d_in[3];
    const float* bih = (const float*)d_in[4];
    const float* bhh = (const float*)d_in[5];
    float* out = (float*)d_out;

    unsigned short* blob0 = (unsigned short*)d_ws;            // 8.39M ushort
    unsigned short* blob1 = blob0 + 8388608L;
    float*          bcJ   = (float*)(blob1 + 8388608L);       // 4096 f32
    unsigned short* hTa   = (unsigned short*)(bcJ + 4096);    // 1M ushort
    unsigned short* hTb   = hTa + 1048576L;
    unsigned int*   bar   = (unsigned int*)(hTb + 1048576L);  // 512 u32

    prep_w  <<<dim3(32768, 2), 256, 0, stream>>>(wih, whh, blob0, blob1);
    prep_bcJ<<<dim3(16),       256, 0, stream>>>(bih, bhh, bcJ, bar);
    prep_h0 <<<dim3(2048),     256, 0, stream>>>(c, hTa);

    void* args[] = { (void*)&blob0, (void*)&blob1, (void*)&hTa, (void*)&hTb,
                     (void*)&c, (void*)&bcJ, (void*)&out, (void*)&bar };
    hipLaunchCooperativeKernel((const void*)gru_all, dim3(256), dim3(512),
                               args, 0, stream);
}

// Round 17
// 1169.728 us; speedup vs baseline: 1.1897x; 1.1897x over previous
//
#include <hip/hip_runtime.h>
#include <math.h>

#define H 1024
#define BATCH 512
#define KSTEPS 96
#define KH ((long)KSTEPS * H)

typedef __attribute__((ext_vector_type(8))) short short8;
typedef __attribute__((ext_vector_type(16))) float f32x16;

__device__ __forceinline__ unsigned short f2bf(float x) {
    union { float f; unsigned int u; } v; v.f = x;
    unsigned int r = v.u + 0x7fffu + ((v.u >> 16) & 1u);
    return (unsigned short)(r >> 16);
}
__device__ __forceinline__ float bf2f(unsigned short h) {
    union { unsigned int u; float f; } v; v.u = ((unsigned int)h) << 16;
    return v.f;
}

// fast saturating gate math (v_exp_f32; NaN-free at +-inf)
__device__ __forceinline__ float fsig(float x)  { return 1.f / (1.f + __expf(-x)); }
__device__ __forceinline__ float ftanh(float x) { return 1.f - 2.f / (1.f + __expf(2.f * x)); }

// async global->LDS 16B/lane; dst wave-uniform base (HW adds lane*16)
__device__ __forceinline__ void glds16(const void* g, void* l) {
    __builtin_amdgcn_global_load_lds(
        (const __attribute__((address_space(1))) void*)g,
        (__attribute__((address_space(3))) void*)l, 16, 0, 0);
}
#define MEMFENCE asm volatile("" ::: "memory")

// ---------------------------------------------------------------------------
// Workspace layouts (32x32x16 MFMA fragment order):
//  blob0/blob1: [32 tc][64 by][2 s][2 jt][2 kg][64 l][8 e] bf16   (W hi+lo)
//  bcJ: [4096] f32 J-interleaved fused biases
//  hTa/hTb: [32 tc][4 bx][2 s][2 mh][2 mt][2 kg][64 l][8 e] bf16 — s=0 only
//  bar: [512] u32 — flag[bx*64+by] at bar[0..255]: steps completed by block
// ---------------------------------------------------------------------------

__global__ void prep_w(const float* __restrict__ wih,
                       const float* __restrict__ whh,
                       unsigned short* __restrict__ blob0,
                       unsigned short* __restrict__ blob1)
{
    const unsigned int f = blockIdx.x * 256 + threadIdx.x;  // 0..8388607
    const int e  = f & 7;
    const int l  = (f >> 3) & 63;
    const int kg = (f >> 9) & 1;
    const int jt = (f >> 10) & 1;
    const int s  = (f >> 11) & 1;
    const int by = (f >> 12) & 63;
    const int tc = (f >> 18) & 31;
    const int b  = blockIdx.y;      // blob select

    const int J = by * 64 + jt * 32 + (l & 31);
    const int g = J & 3;
    const long j = J >> 2;
    const long k = (long)tc * 32 + kg * 16 + (l >> 5) * 8 + e;

    float v = 0.f;
    if (b == 1) {
        if (g == 0)      v = wih[j*1024 + k]           + whh[j*1024 + k];
        else if (g == 1) v = wih[(1024+j)*1024 + k]    + whh[(1024+j)*1024 + k];
        else if (g == 2) v = wih[(2048+j)*1024 + k];
        else             v = whh[(2048+j)*1024 + k];
    } else {
        if (g == 0)      v = whh[j*1024 + k];
        else if (g == 1) v = whh[(1024+j)*1024 + k];
        else if (g == 2) v = 0.f;
        else             v = whh[(2048+j)*1024 + k];
    }
    const unsigned short hi = f2bf(v);
    unsigned short* blob = (b == 0) ? blob0 : blob1;
    blob[f] = (s == 0) ? hi : f2bf(v - bf2f(hi));
}

__global__ void prep_bcJ(const float* __restrict__ bih,
                         const float* __restrict__ bhh,
                         float* __restrict__ bcJ,
                         unsigned int* __restrict__ bar)
{
    const int J = blockIdx.x * 256 + threadIdx.x;   // 0..4095
    const int g = J & 3;
    const int j = J >> 2;
    float v;
    if (g == 0)      v = bih[j]        + bhh[j];
    else if (g == 1) v = bih[1024 + j] + bhh[1024 + j];
    else if (g == 2) v = bih[2048 + j];
    else             v = bhh[2048 + j];
    bcJ[J] = v;
    if (blockIdx.x == 0) {                 // zero flag state (512 u32)
        bar[threadIdx.x]       = 0u;
        bar[256 + threadIdx.x] = 0u;
    }
}

// c [512][1024] fp32 -> hT fragment layout, hi (s=0) only
__global__ void prep_h0(const float* __restrict__ cin,
                        unsigned short* __restrict__ hT)
{
    const unsigned int f = blockIdx.x * 256 + threadIdx.x;   // 0..524287
    const int e  = f & 7;
    const int l  = (f >> 3) & 63;
    const int kg = (f >> 9) & 1;
    const int mt = (f >> 10) & 1;
    const int mh = (f >> 11) & 1;
    const int bx = (f >> 12) & 3;
    const int tc = (f >> 14) & 31;

    const long m = bx * 128 + mh * 64 + mt * 32 + (l & 31);
    const long k = (long)tc * 32 + kg * 16 + (l >> 5) * 8 + e;

    const long addr = (long)tc*32768 + bx*8192 /* s=0 */ + mh*2048 + mt*1024
                    + kg*512 + l*8 + e;
    hT[addr] = f2bf(cin[m * 1024 + k]);
}

// ---------------------------------------------------------------------------
// Persistent GRU: all 96 steps in ONE cooperative launch.
// Grid 256 (1/CU), 512 threads (8 waves). 2-PRODUCT split:
//   W·h ≈ (W_hi + W_lo)·h_hi. 16 MFMA/chunk/wave. r13 K-loop chassis.
// r17: DATAFLOW SYNC — no global rendezvous. Block (bx,by) publishes
//   flag[bx*64+by] = k after all its step-(k-1) hT stores are drained
//   (block-wide __syncthreads orders all waves' vmcnt(0)s before the store).
//   Consumers wait only on their own bx-cohort (64 producer flags), polled
//   by wave 0's lanes; W(0),W(1) staged under the wait.
// Coherence: hT written sc0 sc1 write-through, read sc0 sc1 system-scope;
// out nontemporal; exact h_prev carried in hp[] registers.
// ---------------------------------------------------------------------------
__global__ __launch_bounds__(512) void gru_all(
    const unsigned short* __restrict__ blob0,
    const unsigned short* __restrict__ blob1,
    unsigned short* __restrict__ hTa,
    unsigned short* __restrict__ hTb,
    const float* __restrict__ cin,
    const float* __restrict__ bcJ,
    float* __restrict__ out,
    unsigned int* bar)
{
    __shared__ __attribute__((aligned(16))) char smem[131072]; // W: 4gk x 3 x 8KB; D reuse 128KB

    const int tid  = threadIdx.x;
    const int lane = tid & 63;
    const int wv   = tid >> 6;        // 0..7
    const int gk   = wv >> 1;         // K-quarter 0..3
    const int mh   = wv & 1;          // m-half within 128

    const int id   = blockIdx.x;
    const int grp  = id & 7;
    const int slot = id >> 3;
    const int by   = grp * 8 + (slot & 7);   // 0..63  (J tile)
    const int bx   = slot >> 3;              // 0..3   (m tile)
    const long m0  = (long)bx * 128;

    const float bb0 = bcJ[by*64 + (lane & 31)];
    const float bb1 = bcJ[by*64 + 32 + (lane & 31)];

    // h_prev carried in registers: same (m,j) per thread every step
    float hp[4];
    #pragma unroll
    for (int it = 0; it < 4; ++it) {
        const int qi = it * 512 + tid;
        const int jl = qi & 15;
        const int m  = qi >> 4;
        hp[it] = cin[(m0 + m) * 1024 + (long)by * 16 + jl];
    }

    #pragma unroll 1
    for (int k = 0; k < KSTEPS; ++k) {
        const unsigned short* wbl = (k == 0) ? blob0 : blob1;
        const unsigned short* hTr = (k & 1) ? hTb : hTa;
        unsigned short*       hTw = (k & 1) ? hTa : hTb;
        float* outk = out + (long)k * H;

        const char* wsrc = (const char*)wbl + (long)by * 8192;   // + tc*524288
        const char* hsrc = (const char*)hTr + (long)bx * 16384;  // + tc*65536

        f32x16 acc[2][2];   // [mt][jt]
        {
            const float a0 = (gk == 0) ? bb0 : 0.f;
            const float a1 = (gk == 0) ? bb1 : 0.f;
            #pragma unroll
            for (int mt = 0; mt < 2; ++mt)
                #pragma unroll
                for (int r = 0; r < 16; ++r) { acc[mt][0][r] = a0; acc[mt][1][r] = a1; }
        }

        short8 Aev[4], Aod[4];   // [mt*2+kg], hi only

        auto loadA = [&](int c, short8* A) {
            const char* hs = hsrc + (long)(gk * 8 + c) * 65536;
            #pragma unroll
            for (int mt = 0; mt < 2; ++mt)
                #pragma unroll
                for (int kg = 0; kg < 2; ++kg) {
                    const void* p = hs + (long)(((mh*2+mt)*2)+kg)*1024 + lane*16;
                    asm volatile("global_load_dwordx4 %0, %1, off sc0 sc1"
                                 : "=v"(A[mt*2+kg]) : "v"(p) : "memory");
                }
        };
        auto stageW = [&](int c) {
            const char* ws = wsrc + (long)(gk * 8 + c) * 524288;
            char* dst = smem + gk * 24576 + (c % 3) * 8192;
            #pragma unroll
            for (int o = 0; o < 4; ++o)
                glds16(ws + (mh*4+o)*1024 + lane*16, dst + (mh*4+o)*1024);
        };
        auto compute = [&](const char* wb, const short8* A) {
            #pragma unroll
            for (int kg = 0; kg < 2; ++kg) {
                const short8 bh0 = *(const short8*)(wb + (0*4 + 0*2 + kg)*1024 + lane*16);
                const short8 bh1 = *(const short8*)(wb + (0*4 + 1*2 + kg)*1024 + lane*16);
                const short8 bl0 = *(const short8*)(wb + (1*4 + 0*2 + kg)*1024 + lane*16);
                const short8 bl1 = *(const short8*)(wb + (1*4 + 1*2 + kg)*1024 + lane*16);
                const short8 ah0 = A[0*2 + kg];
                const short8 ah1 = A[1*2 + kg];
                acc[0][0] = __builtin_amdgcn_mfma_f32_32x32x16_bf16(ah0, bh0, acc[0][0], 0, 0, 0);
                acc[0][1] = __builtin_amdgcn_mfma_f32_32x32x16_bf16(ah0, bh1, acc[0][1], 0, 0, 0);
                acc[1][0] = __builtin_amdgcn_mfma_f32_32x32x16_bf16(ah1, bh0, acc[1][0], 0, 0, 0);
                acc[1][1] = __builtin_amdgcn_mfma_f32_32x32x16_bf16(ah1, bh1, acc[1][1], 0, 0, 0);
                acc[0][0] = __builtin_amdgcn_mfma_f32_32x32x16_bf16(ah0, bl0, acc[0][0], 0, 0, 0);
                acc[0][1] = __builtin_amdgcn_mfma_f32_32x32x16_bf16(ah0, bl1, acc[0][1], 0, 0, 0);
                acc[1][0] = __builtin_amdgcn_mfma_f32_32x32x16_bf16(ah1, bl0, acc[1][0], 0, 0, 0);
                acc[1][1] = __builtin_amdgcn_mfma_f32_32x32x16_bf16(ah1, bl1, acc[1][1], 0, 0, 0);
            }
        };

        // ---- step boundary ----
        if (k > 0) {
            __syncthreads();   // ALL waves' epilogue stores drained (per-wave
                               // vmcnt(0) at epilogue tail) + D reads done
            // publish: our step-(k-1) h is globally visible
            if (tid == 0) {
                const unsigned kk = (unsigned)k;
                unsigned int* fp = bar + (bx * 64 + by);
                asm volatile("global_store_dword %0, %1, off sc0 sc1"
                             :: "v"(fp), "v"(kk) : "memory");
            }
        }

        // stage W(0),W(1) under the flag wait (step-independent)
        stageW(0); MEMFENCE;
        stageW(1); MEMFENCE;

        if (k > 0) {
            // wait ONLY on our bx-cohort: 64 producer flags, one per lane
            if (wv == 0) {
                unsigned int* fp = bar + (bx * 64 + lane);
                while (true) {
                    unsigned v;
                    asm volatile("global_load_dword %0, %1, off sc0 sc1\n\t"
                                 "s_waitcnt vmcnt(0)"
                                 : "=v"(v) : "v"(fp) : "memory");
                    if (v >= (unsigned)k) break;
                    __builtin_amdgcn_s_sleep(2);
                }
            }
            __syncthreads();   // release: cohort done -> h(k-1) fully visible
        }

        // ---- A prologue (h-dependent, after release) ----
        loadA(0, Aev); MEMFENCE;
        asm volatile("s_waitcnt vmcnt(0)" ::: "memory");   // A0 + all W stages landed
        __builtin_amdgcn_sched_barrier(0);
        __builtin_amdgcn_s_barrier();

        // r13-proven chunk schedule (steady state identical from chunk 1)
        #define CHUNK(c, Acur, Anext)                                          \
        {                                                                      \
            if ((c) < 7) { loadA((c)+1, Anext); MEMFENCE; }                    \
            if ((c) < 6) { stageW((c)+2); MEMFENCE; }                          \
            __builtin_amdgcn_sched_barrier(0);                                 \
            __builtin_amdgcn_s_setprio(1);                                     \
            compute(smem + gk*24576 + ((c)%3)*8192, Acur);                     \
            __builtin_amdgcn_s_setprio(0);                                     \
            if ((c) <= 5)      asm volatile("s_waitcnt vmcnt(4)" ::: "memory");\
            else if ((c) == 6) asm volatile("s_waitcnt vmcnt(0)" ::: "memory");\
            __builtin_amdgcn_sched_barrier(0);                                 \
            __builtin_amdgcn_s_barrier();                                      \
        }
        CHUNK(0, Aev, Aod) CHUNK(1, Aod, Aev) CHUNK(2, Aev, Aod) CHUNK(3, Aod, Aev)
        CHUNK(4, Aev, Aod) CHUNK(5, Aod, Aev) CHUNK(6, Aev, Aod) CHUNK(7, Aod, Aev)
        #undef CHUNK

        __syncthreads();   // LDS reads done; smem becomes epilogue scratch

        // ---- epilogue: dump partials, 4-way reduce, gates ----
        float* D = (float*)smem;   // [4 gk][128 m][64 J]
        #pragma unroll
        for (int mt = 0; mt < 2; ++mt)
            #pragma unroll
            for (int jt = 0; jt < 2; ++jt)
                #pragma unroll
                for (int r = 0; r < 16; ++r) {
                    const int r32 = (r & 3) + 8 * (r >> 2) + 4 * (lane >> 5);
                    const int m  = mh * 64 + mt * 32 + r32;
                    const int J  = jt * 32 + (lane & 31);
                    D[(gk * 128 + m) * 64 + J] = acc[mt][jt][r];
                }
        __syncthreads();

        #pragma unroll
        for (int it = 0; it < 4; ++it) {
            const int qi = it * 512 + tid;     // 0..2047
            const int jl = qi & 15;
            const int m  = qi >> 4;            // 0..127
            const float4 s0 = *(const float4*)&D[(0*128 + m)*64 + 4*jl];
            const float4 s1 = *(const float4*)&D[(1*128 + m)*64 + 4*jl];
            const float4 s2 = *(const float4*)&D[(2*128 + m)*64 + 4*jl];
            const float4 s3 = *(const float4*)&D[(3*128 + m)*64 + 4*jl];
            const float gr = s0.x + s1.x + s2.x + s3.x;
            const float gz = s0.y + s1.y + s2.y + s3.y;
            const float gi = s0.z + s1.z + s2.z + s3.z;
            const float gh = s0.w + s1.w + s2.w + s3.w;

            const long mg = m0 + m;
            const long j  = (long)by * 16 + jl;

            const float rr = fsig(gr);
            const float zz = fsig(gz);
            const float nn = ftanh(fmaf(rr, gh, gi));
            const float o  = nn + zz * (hp[it] - nn);
            hp[it] = o;

            __builtin_nontemporal_store(o, &outk[mg * KH + j]);

            // hT writeback (hi only) — sc0 sc1 write-through
            const unsigned short hi = f2bf(o);
            const int kk  = (int)j;
            const int tc2 = kk >> 5;
            const int kg2 = (kk >> 4) & 1;
            const int lh  = (kk >> 3) & 1;
            const int e2  = kk & 7;
            const int mh2 = (m >> 6) & 1;
            const int mt2 = (m >> 5) & 1;
            const int row = m & 31;
            const long ub = (long)tc2*32768 + bx*8192 + mh2*2048 + mt2*1024
                          + kg2*512 + (lh*32 + row)*8 + e2;
            unsigned short* p0 = hTw + ub;
            asm volatile("global_store_short %0, %1, off sc0 sc1"
                         :: "v"(p0), "v"((unsigned)hi) : "memory");
        }
        asm volatile("s_waitcnt vmcnt(0)" ::: "memory");   // per-wave drain; ordered
                                                           // block-wide by next-step
                                                           // __syncthreads before flag
    }
}

// ---------------------------------------------------------------------------
extern "C" void kernel_launch(void* const* d_in, const int* in_sizes, int n_in,
                              void* d_out, int out_size, void* d_ws, size_t ws_size,
                              hipStream_t stream)
{
    const float* c   = (const float*)d_in[0];
    // d_in[1] = K (fixed 96)
    const float* wih = (const float*)d_in[2];
    const float* whh = (const float*)d_in[3];
    const float* bih = (const float*)d_in[4];
    const float* bhh = (const float*)d_in[5];
    float* out = (float*)d_out;

    unsigned short* blob0 = (unsigned short*)d_ws;            // 8.39M ushort
    unsigned short* blob1 = blob0 + 8388608L;
    float*          bcJ   = (float*)(blob1 + 8388608L);       // 4096 f32
    unsigned short* hTa   = (unsigned short*)(bcJ + 4096);    // 1M ushort
    unsigned short* hTb   = hTa + 1048576L;
    unsigned int*   bar   = (unsigned int*)(hTb + 1048576L);  // 512 u32

    prep_w  <<<dim3(32768, 2), 256, 0, stream>>>(wih, whh, blob0, blob1);
    prep_bcJ<<<dim3(16),       256, 0, stream>>>(bih, bhh, bcJ, bar);
    prep_h0 <<<dim3(2048),     256, 0, stream>>>(c, hTa);

    void* args[] = { (void*)&blob0, (void*)&blob1, (void*)&hTa, (void*)&hTb,
                     (void*)&c, (void*)&bcJ, (void*)&out, (void*)&bar };
    hipLaunchCooperativeKernel((const void*)gru_all, dim3(256), dim3(512),
                               args, 0, stream);
}

// Round 18
// 1163.470 us; speedup vs baseline: 1.1961x; 1.0054x over previous
//
#include <hip/hip_runtime.h>
#include <math.h>

#define H 1024
#define BATCH 512
#define KSTEPS 96
#define KH ((long)KSTEPS * H)

typedef __attribute__((ext_vector_type(8))) short short8;
typedef __attribute__((ext_vector_type(16))) float f32x16;

__device__ __forceinline__ unsigned short f2bf(float x) {
    union { float f; unsigned int u; } v; v.f = x;
    unsigned int r = v.u + 0x7fffu + ((v.u >> 16) & 1u);
    return (unsigned short)(r >> 16);
}
__device__ __forceinline__ float bf2f(unsigned short h) {
    union { unsigned int u; float f; } v; v.u = ((unsigned int)h) << 16;
    return v.f;
}

// fast saturating gate math (v_exp_f32; NaN-free at +-inf)
__device__ __forceinline__ float fsig(float x)  { return 1.f / (1.f + __expf(-x)); }
__device__ __forceinline__ float ftanh(float x) { return 1.f - 2.f / (1.f + __expf(2.f * x)); }

// async global->LDS 16B/lane; dst wave-uniform base (HW adds lane*16)
__device__ __forceinline__ void glds16(const void* g, void* l) {
    __builtin_amdgcn_global_load_lds(
        (const __attribute__((address_space(1))) void*)g,
        (__attribute__((address_space(3))) void*)l, 16, 0, 0);
}
#define MEMFENCE asm volatile("" ::: "memory")

// ---------------------------------------------------------------------------
// Workspace layouts (32x32x16 MFMA fragment order):
//  blob0/blob1: [32 tc][64 by][2 s][2 jt][2 kg][64 l][8 e] bf16   (W hi+lo)
//  bcJ: [4096] f32 J-interleaved fused biases
//  hTa/hTb: [32 tc][4 bx][2 s][2 mh][2 mt][2 kg][64 l][8 e] bf16 — s=0 only
//  bar: [512] u32 — flag[bx*64+by] at bar[0..255]: steps globally visible
// ---------------------------------------------------------------------------

__global__ void prep_w(const float* __restrict__ wih,
                       const float* __restrict__ whh,
                       unsigned short* __restrict__ blob0,
                       unsigned short* __restrict__ blob1)
{
    const unsigned int f = blockIdx.x * 256 + threadIdx.x;  // 0..8388607
    const int e  = f & 7;
    const int l  = (f >> 3) & 63;
    const int kg = (f >> 9) & 1;
    const int jt = (f >> 10) & 1;
    const int s  = (f >> 11) & 1;
    const int by = (f >> 12) & 63;
    const int tc = (f >> 18) & 31;
    const int b  = blockIdx.y;      // blob select

    const int J = by * 64 + jt * 32 + (l & 31);
    const int g = J & 3;
    const long j = J >> 2;
    const long k = (long)tc * 32 + kg * 16 + (l >> 5) * 8 + e;

    float v = 0.f;
    if (b == 1) {
        if (g == 0)      v = wih[j*1024 + k]           + whh[j*1024 + k];
        else if (g == 1) v = wih[(1024+j)*1024 + k]    + whh[(1024+j)*1024 + k];
        else if (g == 2) v = wih[(2048+j)*1024 + k];
        else             v = whh[(2048+j)*1024 + k];
    } else {
        if (g == 0)      v = whh[j*1024 + k];
        else if (g == 1) v = whh[(1024+j)*1024 + k];
        else if (g == 2) v = 0.f;
        else             v = whh[(2048+j)*1024 + k];
    }
    const unsigned short hi = f2bf(v);
    unsigned short* blob = (b == 0) ? blob0 : blob1;
    blob[f] = (s == 0) ? hi : f2bf(v - bf2f(hi));
}

__global__ void prep_bcJ(const float* __restrict__ bih,
                         const float* __restrict__ bhh,
                         float* __restrict__ bcJ,
                         unsigned int* __restrict__ bar)
{
    const int J = blockIdx.x * 256 + threadIdx.x;   // 0..4095
    const int g = J & 3;
    const int j = J >> 2;
    float v;
    if (g == 0)      v = bih[j]        + bhh[j];
    else if (g == 1) v = bih[1024 + j] + bhh[1024 + j];
    else if (g == 2) v = bih[2048 + j];
    else             v = bhh[2048 + j];
    bcJ[J] = v;
    if (blockIdx.x == 0) {                 // zero flag state (512 u32)
        bar[threadIdx.x]       = 0u;
        bar[256 + threadIdx.x] = 0u;
    }
}

// c [512][1024] fp32 -> hT fragment layout, hi (s=0) only
__global__ void prep_h0(const float* __restrict__ cin,
                        unsigned short* __restrict__ hT)
{
    const unsigned int f = blockIdx.x * 256 + threadIdx.x;   // 0..524287
    const int e  = f & 7;
    const int l  = (f >> 3) & 63;
    const int kg = (f >> 9) & 1;
    const int mt = (f >> 10) & 1;
    const int mh = (f >> 11) & 1;
    const int bx = (f >> 12) & 3;
    const int tc = (f >> 14) & 31;

    const long m = bx * 128 + mh * 64 + mt * 32 + (l & 31);
    const long k = (long)tc * 32 + kg * 16 + (l >> 5) * 8 + e;

    const long addr = (long)tc*32768 + bx*8192 /* s=0 */ + mh*2048 + mt*1024
                    + kg*512 + l*8 + e;
    hT[addr] = f2bf(cin[m * 1024 + k]);
}

// ---------------------------------------------------------------------------
// Persistent GRU: all 96 steps in ONE cooperative launch.
// Grid 256 (1/CU), 512 threads (8 waves). 2-PRODUCT split:
//   W·h ≈ (W_hi + W_lo)·h_hi. 16 MFMA/chunk/wave.
// r18 = r17 dataflow sync +
//   (1) epilogue split: hT stores + drain + FLAG first; out-stores issued
//       after (drain overlaps the next cohort wait) — HBM store latency is
//       off the producer->consumer critical path.
//   (2) A prefetched 2 chunks deep (3 rotating sets, vmcnt(8) per chunk).
//   (3) next step's W(0),W(1) pre-staged at the epilogue tail.
// Coherence: hT written sc0 sc1 write-through, read sc0 sc1 system-scope;
// out nontemporal; exact h_prev carried in hp[] registers.
// ---------------------------------------------------------------------------
__global__ __launch_bounds__(512) void gru_all(
    const unsigned short* __restrict__ blob0,
    const unsigned short* __restrict__ blob1,
    unsigned short* __restrict__ hTa,
    unsigned short* __restrict__ hTb,
    const float* __restrict__ cin,
    const float* __restrict__ bcJ,
    float* __restrict__ out,
    unsigned int* bar)
{
    __shared__ __attribute__((aligned(16))) char smem[131072]; // W: 4gk x 3 x 8KB; D reuse 128KB

    const int tid  = threadIdx.x;
    const int lane = tid & 63;
    const int wv   = tid >> 6;        // 0..7
    const int gk   = wv >> 1;         // K-quarter 0..3
    const int mh   = wv & 1;          // m-half within 128

    const int id   = blockIdx.x;
    const int grp  = id & 7;
    const int slot = id >> 3;
    const int by   = grp * 8 + (slot & 7);   // 0..63  (J tile)
    const int bx   = slot >> 3;              // 0..3   (m tile)
    const long m0  = (long)bx * 128;

    const float bb0 = bcJ[by*64 + (lane & 31)];
    const float bb1 = bcJ[by*64 + 32 + (lane & 31)];

    const char* wsrc0 = (const char*)blob0 + (long)by * 8192;  // + tc*524288
    const char* wsrc1 = (const char*)blob1 + (long)by * 8192;

    // stage W chunk c (4 glds16/wave) into buf c%3 of this gk
    auto stageW = [&](const char* wsb, int c) {
        const char* ws = wsb + (long)(gk * 8 + c) * 524288;
        char* dst = smem + gk * 24576 + (c % 3) * 8192;
        #pragma unroll
        for (int o = 0; o < 4; ++o)
            glds16(ws + (mh*4+o)*1024 + lane*16, dst + (mh*4+o)*1024);
    };

    // h_prev carried in registers: same (m,j) per thread every step
    float hp[4];
    #pragma unroll
    for (int it = 0; it < 4; ++it) {
        const int qi = it * 512 + tid;
        const int jl = qi & 15;
        const int m  = qi >> 4;
        hp[it] = cin[(m0 + m) * 1024 + (long)by * 16 + jl];
    }

    // pre-stage W(0),W(1) for step 0 (blob0)
    stageW(wsrc0, 0); MEMFENCE;
    stageW(wsrc0, 1); MEMFENCE;

    #pragma unroll 1
    for (int k = 0; k < KSTEPS; ++k) {
        const char* wsrc = (k == 0) ? wsrc0 : wsrc1;
        const unsigned short* hTr = (k & 1) ? hTb : hTa;
        unsigned short*       hTw = (k & 1) ? hTa : hTb;
        float* outk = out + (long)k * H;

        const char* hsrc = (const char*)hTr + (long)bx * 16384;  // + tc*65536

        f32x16 acc[2][2];   // [mt][jt]
        {
            const float a0 = (gk == 0) ? bb0 : 0.f;
            const float a1 = (gk == 0) ? bb1 : 0.f;
            #pragma unroll
            for (int mt = 0; mt < 2; ++mt)
                #pragma unroll
                for (int r = 0; r < 16; ++r) { acc[mt][0][r] = a0; acc[mt][1][r] = a1; }
        }

        short8 A0[4], A1[4], A2[4];   // 3 rotating sets, [mt*2+kg], hi only

        auto loadA = [&](int c, short8* A) {
            const char* hs = hsrc + (long)(gk * 8 + c) * 65536;
            #pragma unroll
            for (int mt = 0; mt < 2; ++mt)
                #pragma unroll
                for (int kg = 0; kg < 2; ++kg) {
                    const void* p = hs + (long)(((mh*2+mt)*2)+kg)*1024 + lane*16;
                    asm volatile("global_load_dwordx4 %0, %1, off sc0 sc1"
                                 : "=v"(A[mt*2+kg]) : "v"(p) : "memory");
                }
        };
        auto compute = [&](const char* wb, const short8* A) {
            #pragma unroll
            for (int kg = 0; kg < 2; ++kg) {
                const short8 bh0 = *(const short8*)(wb + (0*4 + 0*2 + kg)*1024 + lane*16);
                const short8 bh1 = *(const short8*)(wb + (0*4 + 1*2 + kg)*1024 + lane*16);
                const short8 bl0 = *(const short8*)(wb + (1*4 + 0*2 + kg)*1024 + lane*16);
                const short8 bl1 = *(const short8*)(wb + (1*4 + 1*2 + kg)*1024 + lane*16);
                const short8 ah0 = A[0*2 + kg];
                const short8 ah1 = A[1*2 + kg];
                acc[0][0] = __builtin_amdgcn_mfma_f32_32x32x16_bf16(ah0, bh0, acc[0][0], 0, 0, 0);
                acc[0][1] = __builtin_amdgcn_mfma_f32_32x32x16_bf16(ah0, bh1, acc[0][1], 0, 0, 0);
                acc[1][0] = __builtin_amdgcn_mfma_f32_32x32x16_bf16(ah1, bh0, acc[1][0], 0, 0, 0);
                acc[1][1] = __builtin_amdgcn_mfma_f32_32x32x16_bf16(ah1, bh1, acc[1][1], 0, 0, 0);
                acc[0][0] = __builtin_amdgcn_mfma_f32_32x32x16_bf16(ah0, bl0, acc[0][0], 0, 0, 0);
                acc[0][1] = __builtin_amdgcn_mfma_f32_32x32x16_bf16(ah0, bl1, acc[0][1], 0, 0, 0);
                acc[1][0] = __builtin_amdgcn_mfma_f32_32x32x16_bf16(ah1, bl0, acc[1][0], 0, 0, 0);
                acc[1][1] = __builtin_amdgcn_mfma_f32_32x32x16_bf16(ah1, bl1, acc[1][1], 0, 0, 0);
            }
        };

        // ---- cohort wait: our bx-slice producers done with step k-1 ----
        if (k > 0) {
            if (wv == 0) {
                unsigned int* fp = bar + (bx * 64 + lane);
                while (true) {
                    unsigned v;
                    asm volatile("global_load_dword %0, %1, off sc0 sc1\n\t"
                                 "s_waitcnt vmcnt(0)"
                                 : "=v"(v) : "v"(fp) : "memory");
                    if (v >= (unsigned)k) break;
                    __builtin_amdgcn_s_sleep(2);
                }
            }
            __syncthreads();   // release; h(k-1) globally visible
        }

        // ---- A prologue: 2 chunks in flight ----
        loadA(0, A0); MEMFENCE;
        loadA(1, A1); MEMFENCE;
        // per-wave FIFO (worst case): [out4][W8][A0:4][A1:4] -> vmcnt(4)
        // drains everything except A1: W(0),W(1),A0 guaranteed landed.
        asm volatile("s_waitcnt vmcnt(4)" ::: "memory");
        __builtin_amdgcn_sched_barrier(0);
        __builtin_amdgcn_s_barrier();

        // chunk c: issue A(c+2),W(c+2); compute(c); vmcnt(8) drains
        // A(c+1),W(c+1) (one full chunk of cover); barrier.
        #define CHUNK(c, Ac, An)                                               \
        {                                                                      \
            if ((c) <= 5) { loadA((c)+2, An); MEMFENCE;                        \
                            stageW(wsrc, (c)+2); MEMFENCE; }                   \
            __builtin_amdgcn_sched_barrier(0);                                 \
            __builtin_amdgcn_s_setprio(1);                                     \
            compute(smem + gk*24576 + ((c)%3)*8192, Ac);                       \
            __builtin_amdgcn_s_setprio(0);                                     \
            if ((c) <= 5)      asm volatile("s_waitcnt vmcnt(8)" ::: "memory");\
            else if ((c) == 6) asm volatile("s_waitcnt vmcnt(0)" ::: "memory");\
            __builtin_amdgcn_sched_barrier(0);                                 \
            __builtin_amdgcn_s_barrier();                                      \
        }
        CHUNK(0, A0, A2) CHUNK(1, A1, A0) CHUNK(2, A2, A1) CHUNK(3, A0, A2)
        CHUNK(4, A1, A0) CHUNK(5, A2, A1) CHUNK(6, A0, A2) CHUNK(7, A1, A0)
        #undef CHUNK

        __syncthreads();   // LDS reads done; smem becomes epilogue scratch

        // ---- epilogue: dump partials, 4-way reduce ----
        float* D = (float*)smem;   // [4 gk][128 m][64 J]
        #pragma unroll
        for (int mt = 0; mt < 2; ++mt)
            #pragma unroll
            for (int jt = 0; jt < 2; ++jt)
                #pragma unroll
                for (int r = 0; r < 16; ++r) {
                    const int r32 = (r & 3) + 8 * (r >> 2) + 4 * (lane >> 5);
                    const int m  = mh * 64 + mt * 32 + r32;
                    const int J  = jt * 32 + (lane & 31);
                    D[(gk * 128 + m) * 64 + J] = acc[mt][jt][r];
                }
        __syncthreads();

        // ---- loop A: gates + hT stores ONLY (producer critical path) ----
        #pragma unroll
        for (int it = 0; it < 4; ++it) {
            const int qi = it * 512 + tid;     // 0..2047
            const int jl = qi & 15;
            const int m  = qi >> 4;            // 0..127
            const float4 s0 = *(const float4*)&D[(0*128 + m)*64 + 4*jl];
            const float4 s1 = *(const float4*)&D[(1*128 + m)*64 + 4*jl];
            const float4 s2 = *(const float4*)&D[(2*128 + m)*64 + 4*jl];
            const float4 s3 = *(const float4*)&D[(3*128 + m)*64 + 4*jl];
            const float gr = s0.x + s1.x + s2.x + s3.x;
            const float gz = s0.y + s1.y + s2.y + s3.y;
            const float gi = s0.z + s1.z + s2.z + s3.z;
            const float gh = s0.w + s1.w + s2.w + s3.w;

            const long j = (long)by * 16 + jl;

            const float rr = fsig(gr);
            const float zz = fsig(gz);
            const float nn = ftanh(fmaf(rr, gh, gi));
            const float o  = nn + zz * (hp[it] - nn);
            hp[it] = o;

            // hT writeback (hi only) — sc0 sc1 write-through
            const unsigned short hi = f2bf(o);
            const int kk  = (int)j;
            const int tc2 = kk >> 5;
            const int kg2 = (kk >> 4) & 1;
            const int lh  = (kk >> 3) & 1;
            const int e2  = kk & 7;
            const int mh2 = (m >> 6) & 1;
            const int mt2 = (m >> 5) & 1;
            const int row = m & 31;
            const long ub = (long)tc2*32768 + bx*8192 + mh2*2048 + mt2*1024
                          + kg2*512 + (lh*32 + row)*8 + e2;
            unsigned short* p0 = hTw + ub;
            asm volatile("global_store_short %0, %1, off sc0 sc1"
                         :: "v"(p0), "v"((unsigned)hi) : "memory");
        }
        asm volatile("s_waitcnt vmcnt(0)" ::: "memory");   // hT drained (out not yet issued)
        __syncthreads();                                   // all waves drained

        // ---- publish EARLY, then pre-stage next W, then out-stores ----
        if (k < KSTEPS - 1) {
            if (tid == 0) {
                const unsigned kk = (unsigned)(k + 1);
                unsigned int* fp = bar + (bx * 64 + by);
                asm volatile("global_store_dword %0, %1, off sc0 sc1"
                             :: "v"(fp), "v"(kk) : "memory");
            }
            stageW(wsrc1, 0); MEMFENCE;
            stageW(wsrc1, 1); MEMFENCE;
        }

        // loop B: out stores (nontemporal; drain overlaps next cohort wait)
        #pragma unroll
        for (int it = 0; it < 4; ++it) {
            const int qi = it * 512 + tid;
            const int jl = qi & 15;
            const int m  = qi >> 4;
            const long mg = m0 + m;
            const long j  = (long)by * 16 + jl;
            __builtin_nontemporal_store(hp[it], &outk[mg * KH + j]);
        }
    }
}

// ---------------------------------------------------------------------------
extern "C" void kernel_launch(void* const* d_in, const int* in_sizes, int n_in,
                              void* d_out, int out_size, void* d_ws, size_t ws_size,
                              hipStream_t stream)
{
    const float* c   = (const float*)d_in[0];
    // d_in[1] = K (fixed 96)
    const float* wih = (const float*)d_in[2];
    const float* whh = (const float*)d_in[3];
    const float* bih = (const float*)d_in[4];
    const float* bhh = (const float*)d_in[5];
    float* out = (float*)d_out;

    unsigned short* blob0 = (unsigned short*)d_ws;            // 8.39M ushort
    unsigned short* blob1 = blob0 + 8388608L;
    float*          bcJ   = (float*)(blob1 + 8388608L);       // 4096 f32
    unsigned short* hTa   = (unsigned short*)(bcJ + 4096);    // 1M ushort
    unsigned short* hTb   = hTa + 1048576L;
    unsigned int*   bar   = (unsigned int*)(hTb + 1048576L);  // 512 u32

    prep_w  <<<dim3(32768, 2), 256, 0, stream>>>(wih, whh, blob0, blob1);
    prep_bcJ<<<dim3(16),       256, 0, stream>>>(bih, bhh, bcJ, bar);
    prep_h0 <<<dim3(2048),     256, 0, stream>>>(c, hTa);

    void* args[] = { (void*)&blob0, (void*)&blob1, (void*)&hTa, (void*)&hTb,
                     (void*)&c, (void*)&bcJ, (void*)&out, (void*)&bar };
    hipLaunchCooperativeKernel((const void*)gru_all, dim3(256), dim3(512),
                               args, 0, stream);
}

// Round 19
// 875.265 us; speedup vs baseline: 1.5899x; 1.3293x over previous
//
#include <hip/hip_runtime.h>
#include <math.h>

#define H 1024
#define BATCH 512
#define KSTEPS 96
#define KH ((long)KSTEPS * H)

typedef __attribute__((ext_vector_type(8))) short short8;
typedef __attribute__((ext_vector_type(16))) float f32x16;

__device__ __forceinline__ unsigned short f2bf(float x) {
    union { float f; unsigned int u; } v; v.f = x;
    unsigned int r = v.u + 0x7fffu + ((v.u >> 16) & 1u);
    return (unsigned short)(r >> 16);
}
__device__ __forceinline__ float bf2f(unsigned short h) {
    union { unsigned int u; float f; } v; v.u = ((unsigned int)h) << 16;
    return v.f;
}

// fast saturating gate math (v_exp_f32; NaN-free at +-inf)
__device__ __forceinline__ float fsig(float x)  { return 1.f / (1.f + __expf(-x)); }
__device__ __forceinline__ float ftanh(float x) { return 1.f - 2.f / (1.f + __expf(2.f * x)); }

// async global->LDS 16B/lane; dst wave-uniform base (HW adds lane*16)
__device__ __forceinline__ void glds16(const void* g, void* l) {
    __builtin_amdgcn_global_load_lds(
        (const __attribute__((address_space(1))) void*)g,
        (__attribute__((address_space(3))) void*)l, 16, 0, 0);
}
#define MEMFENCE asm volatile("" ::: "memory")

// ---------------------------------------------------------------------------
// Workspace layouts (32x32x16 MFMA fragment order):
//  blob0/blob1: [32 tc][64 by][2 s][2 jt][2 kg][64 l][8 e] bf16 (hi+lo kept;
//               r19 kernel reads s=0 (hi) ONLY — pure-bf16 1-product)
//  bcJ: [4096] f32 J-interleaved fused biases
//  hTa/hTb: [32 tc][4 bx][2 s][2 mh][2 mt][2 kg][64 l][8 e] bf16 — s=0 only
//  bar: [512] u32 — flag[bx*64+by] at bar[0..255]: steps globally visible
// ---------------------------------------------------------------------------

__global__ void prep_w(const float* __restrict__ wih,
                       const float* __restrict__ whh,
                       unsigned short* __restrict__ blob0,
                       unsigned short* __restrict__ blob1)
{
    const unsigned int f = blockIdx.x * 256 + threadIdx.x;  // 0..8388607
    const int e  = f & 7;
    const int l  = (f >> 3) & 63;
    const int kg = (f >> 9) & 1;
    const int jt = (f >> 10) & 1;
    const int s  = (f >> 11) & 1;
    const int by = (f >> 12) & 63;
    const int tc = (f >> 18) & 31;
    const int b  = blockIdx.y;      // blob select

    const int J = by * 64 + jt * 32 + (l & 31);
    const int g = J & 3;
    const long j = J >> 2;
    const long k = (long)tc * 32 + kg * 16 + (l >> 5) * 8 + e;

    float v = 0.f;
    if (b == 1) {
        if (g == 0)      v = wih[j*1024 + k]           + whh[j*1024 + k];
        else if (g == 1) v = wih[(1024+j)*1024 + k]    + whh[(1024+j)*1024 + k];
        else if (g == 2) v = wih[(2048+j)*1024 + k];
        else             v = whh[(2048+j)*1024 + k];
    } else {
        if (g == 0)      v = whh[j*1024 + k];
        else if (g == 1) v = whh[(1024+j)*1024 + k];
        else if (g == 2) v = 0.f;
        else             v = whh[(2048+j)*1024 + k];
    }
    const unsigned short hi = f2bf(v);
    unsigned short* blob = (b == 0) ? blob0 : blob1;
    blob[f] = (s == 0) ? hi : f2bf(v - bf2f(hi));
}

__global__ void prep_bcJ(const float* __restrict__ bih,
                         const float* __restrict__ bhh,
                         float* __restrict__ bcJ,
                         unsigned int* __restrict__ bar)
{
    const int J = blockIdx.x * 256 + threadIdx.x;   // 0..4095
    const int g = J & 3;
    const int j = J >> 2;
    float v;
    if (g == 0)      v = bih[j]        + bhh[j];
    else if (g == 1) v = bih[1024 + j] + bhh[1024 + j];
    else if (g == 2) v = bih[2048 + j];
    else             v = bhh[2048 + j];
    bcJ[J] = v;
    if (blockIdx.x == 0) {                 // zero flag state (512 u32)
        bar[threadIdx.x]       = 0u;
        bar[256 + threadIdx.x] = 0u;
    }
}

// c [512][1024] fp32 -> hT fragment layout, hi (s=0) only
__global__ void prep_h0(const float* __restrict__ cin,
                        unsigned short* __restrict__ hT)
{
    const unsigned int f = blockIdx.x * 256 + threadIdx.x;   // 0..524287
    const int e  = f & 7;
    const int l  = (f >> 3) & 63;
    const int kg = (f >> 9) & 1;
    const int mt = (f >> 10) & 1;
    const int mh = (f >> 11) & 1;
    const int bx = (f >> 12) & 3;
    const int tc = (f >> 14) & 31;

    const long m = bx * 128 + mh * 64 + mt * 32 + (l & 31);
    const long k = (long)tc * 32 + kg * 16 + (l >> 5) * 8 + e;

    const long addr = (long)tc*32768 + bx*8192 /* s=0 */ + mh*2048 + mt*1024
                    + kg*512 + l*8 + e;
    hT[addr] = f2bf(cin[m * 1024 + k]);
}

// ---------------------------------------------------------------------------
// Persistent GRU: all 96 steps in ONE cooperative launch.
// Grid 256 (1/CU), 512 threads (8 waves).
// r19: PURE-BF16 1-PRODUCT — W_hi · h_hi (exact fp32 h carried in hp[] regs,
//   so W-rounding is a fixed weight perturbation, h-rounding non-accumulating).
//   8 MFMA/chunk/wave; W stage = 2 glds16/wave (4 KB hi-only); W LDS 48 KB.
// Chassis = r18: dataflow cohort sync, epilogue split (hT+flag before out),
// A 2-deep (3 rotating sets), W pre-staged at epilogue tail.
// Coherence: hT written sc0 sc1 write-through, read sc0 sc1 system-scope;
// out nontemporal; exact h_prev in hp[] registers.
// ---------------------------------------------------------------------------
__global__ __launch_bounds__(512) void gru_all(
    const unsigned short* __restrict__ blob0,
    const unsigned short* __restrict__ blob1,
    unsigned short* __restrict__ hTa,
    unsigned short* __restrict__ hTb,
    const float* __restrict__ cin,
    const float* __restrict__ bcJ,
    float* __restrict__ out,
    unsigned int* bar)
{
    __shared__ __attribute__((aligned(16))) char smem[131072]; // W: 4gk x 3 x 4KB = 48KB; D 128KB reuse

    const int tid  = threadIdx.x;
    const int lane = tid & 63;
    const int wv   = tid >> 6;        // 0..7
    const int gk   = wv >> 1;         // K-quarter 0..3
    const int mh   = wv & 1;          // m-half within 128

    const int id   = blockIdx.x;
    const int grp  = id & 7;
    const int slot = id >> 3;
    const int by   = grp * 8 + (slot & 7);   // 0..63  (J tile)
    const int bx   = slot >> 3;              // 0..3   (m tile)
    const long m0  = (long)bx * 128;

    const float bb0 = bcJ[by*64 + (lane & 31)];
    const float bb1 = bcJ[by*64 + 32 + (lane & 31)];

    const char* wsrc0 = (const char*)blob0 + (long)by * 8192;  // + tc*524288
    const char* wsrc1 = (const char*)blob1 + (long)by * 8192;

    // stage W chunk c, hi-only (2 glds16/wave, 4 KB per gk-buf)
    auto stageW = [&](const char* wsb, int c) {
        const char* ws = wsb + (long)(gk * 8 + c) * 524288;   // s=0 = first 4KB
        char* dst = smem + gk * 12288 + (c % 3) * 4096;
        #pragma unroll
        for (int o = 0; o < 2; ++o)
            glds16(ws + (mh*2+o)*1024 + lane*16, dst + (mh*2+o)*1024);
    };

    // h_prev carried in registers: same (m,j) per thread every step
    float hp[4];
    #pragma unroll
    for (int it = 0; it < 4; ++it) {
        const int qi = it * 512 + tid;
        const int jl = qi & 15;
        const int m  = qi >> 4;
        hp[it] = cin[(m0 + m) * 1024 + (long)by * 16 + jl];
    }

    // pre-stage W(0),W(1) for step 0 (blob0)
    stageW(wsrc0, 0); MEMFENCE;
    stageW(wsrc0, 1); MEMFENCE;

    #pragma unroll 1
    for (int k = 0; k < KSTEPS; ++k) {
        const char* wsrc = (k == 0) ? wsrc0 : wsrc1;
        const unsigned short* hTr = (k & 1) ? hTb : hTa;
        unsigned short*       hTw = (k & 1) ? hTa : hTb;
        float* outk = out + (long)k * H;

        const char* hsrc = (const char*)hTr + (long)bx * 16384;  // + tc*65536

        f32x16 acc[2][2];   // [mt][jt]
        {
            const float a0 = (gk == 0) ? bb0 : 0.f;
            const float a1 = (gk == 0) ? bb1 : 0.f;
            #pragma unroll
            for (int mt = 0; mt < 2; ++mt)
                #pragma unroll
                for (int r = 0; r < 16; ++r) { acc[mt][0][r] = a0; acc[mt][1][r] = a1; }
        }

        short8 A0[4], A1[4], A2[4];   // 3 rotating sets, [mt*2+kg], hi only

        auto loadA = [&](int c, short8* A) {
            const char* hs = hsrc + (long)(gk * 8 + c) * 65536;
            #pragma unroll
            for (int mt = 0; mt < 2; ++mt)
                #pragma unroll
                for (int kg = 0; kg < 2; ++kg) {
                    const void* p = hs + (long)(((mh*2+mt)*2)+kg)*1024 + lane*16;
                    asm volatile("global_load_dwordx4 %0, %1, off sc0 sc1"
                                 : "=v"(A[mt*2+kg]) : "v"(p) : "memory");
                }
        };
        auto compute = [&](const char* wb, const short8* A) {
            #pragma unroll
            for (int kg = 0; kg < 2; ++kg) {
                const short8 bh0 = *(const short8*)(wb + (0*2 + kg)*1024 + lane*16);
                const short8 bh1 = *(const short8*)(wb + (1*2 + kg)*1024 + lane*16);
                const short8 ah0 = A[0*2 + kg];
                const short8 ah1 = A[1*2 + kg];
                // 4 independent chains, 8 MFMA total per chunk
                acc[0][0] = __builtin_amdgcn_mfma_f32_32x32x16_bf16(ah0, bh0, acc[0][0], 0, 0, 0);
                acc[0][1] = __builtin_amdgcn_mfma_f32_32x32x16_bf16(ah0, bh1, acc[0][1], 0, 0, 0);
                acc[1][0] = __builtin_amdgcn_mfma_f32_32x32x16_bf16(ah1, bh0, acc[1][0], 0, 0, 0);
                acc[1][1] = __builtin_amdgcn_mfma_f32_32x32x16_bf16(ah1, bh1, acc[1][1], 0, 0, 0);
            }
        };

        // ---- cohort wait: our bx-slice producers done with step k-1 ----
        if (k > 0) {
            if (wv == 0) {
                unsigned int* fp = bar + (bx * 64 + lane);
                while (true) {
                    unsigned v;
                    asm volatile("global_load_dword %0, %1, off sc0 sc1\n\t"
                                 "s_waitcnt vmcnt(0)"
                                 : "=v"(v) : "v"(fp) : "memory");
                    if (v >= (unsigned)k) break;
                    __builtin_amdgcn_s_sleep(2);
                }
            }
            __syncthreads();   // release; h(k-1) globally visible
        }

        // ---- A prologue: 2 chunks in flight ----
        loadA(0, A0); MEMFENCE;
        loadA(1, A1); MEMFENCE;
        // per-wave FIFO (worst case): [out4][W0:2][W1:2][A0:4][A1:4] ->
        // vmcnt(4) drains everything except A1: W(0),W(1),A0 landed.
        asm volatile("s_waitcnt vmcnt(4)" ::: "memory");
        __builtin_amdgcn_sched_barrier(0);
        __builtin_amdgcn_s_barrier();

        // chunk c: issue A(c+2) [4] + W(c+2) [2]; compute(c); vmcnt(6) drains
        // A(c+1),W(c+1) (one full chunk of cover); barrier.
        #define CHUNK(c, Ac, An)                                               \
        {                                                                      \
            if ((c) <= 5) { loadA((c)+2, An); MEMFENCE;                        \
                            stageW(wsrc, (c)+2); MEMFENCE; }                   \
            __builtin_amdgcn_sched_barrier(0);                                 \
            __builtin_amdgcn_s_setprio(1);                                     \
            compute(smem + gk*12288 + ((c)%3)*4096, Ac);                       \
            __builtin_amdgcn_s_setprio(0);                                     \
            if ((c) <= 5)      asm volatile("s_waitcnt vmcnt(6)" ::: "memory");\
            else if ((c) == 6) asm volatile("s_waitcnt vmcnt(0)" ::: "memory");\
            __builtin_amdgcn_sched_barrier(0);                                 \
            __builtin_amdgcn_s_barrier();                                      \
        }
        CHUNK(0, A0, A2) CHUNK(1, A1, A0) CHUNK(2, A2, A1) CHUNK(3, A0, A2)
        CHUNK(4, A1, A0) CHUNK(5, A2, A1) CHUNK(6, A0, A2) CHUNK(7, A1, A0)
        #undef CHUNK

        __syncthreads();   // LDS W reads done; smem becomes epilogue scratch

        // ---- epilogue: dump partials, 4-way reduce ----
        float* D = (float*)smem;   // [4 gk][128 m][64 J]
        #pragma unroll
        for (int mt = 0; mt < 2; ++mt)
            #pragma unroll
            for (int jt = 0; jt < 2; ++jt)
                #pragma unroll
                for (int r = 0; r < 16; ++r) {
                    const int r32 = (r & 3) + 8 * (r >> 2) + 4 * (lane >> 5);
                    const int m  = mh * 64 + mt * 32 + r32;
                    const int J  = jt * 32 + (lane & 31);
                    D[(gk * 128 + m) * 64 + J] = acc[mt][jt][r];
                }
        __syncthreads();

        // ---- loop A: gates + hT stores ONLY (producer critical path) ----
        #pragma unroll
        for (int it = 0; it < 4; ++it) {
            const int qi = it * 512 + tid;     // 0..2047
            const int jl = qi & 15;
            const int m  = qi >> 4;            // 0..127
            const float4 s0 = *(const float4*)&D[(0*128 + m)*64 + 4*jl];
            const float4 s1 = *(const float4*)&D[(1*128 + m)*64 + 4*jl];
            const float4 s2 = *(const float4*)&D[(2*128 + m)*64 + 4*jl];
            const float4 s3 = *(const float4*)&D[(3*128 + m)*64 + 4*jl];
            const float gr = s0.x + s1.x + s2.x + s3.x;
            const float gz = s0.y + s1.y + s2.y + s3.y;
            const float gi = s0.z + s1.z + s2.z + s3.z;
            const float gh = s0.w + s1.w + s2.w + s3.w;

            const long j = (long)by * 16 + jl;

            const float rr = fsig(gr);
            const float zz = fsig(gz);
            const float nn = ftanh(fmaf(rr, gh, gi));
            const float o  = nn + zz * (hp[it] - nn);
            hp[it] = o;

            // hT writeback (hi only) — sc0 sc1 write-through
            const unsigned short hi = f2bf(o);
            const int kk  = (int)j;
            const int tc2 = kk >> 5;
            const int kg2 = (kk >> 4) & 1;
            const int lh  = (kk >> 3) & 1;
            const int e2  = kk & 7;
            const int mh2 = (m >> 6) & 1;
            const int mt2 = (m >> 5) & 1;
            const int row = m & 31;
            const long ub = (long)tc2*32768 + bx*8192 + mh2*2048 + mt2*1024
                          + kg2*512 + (lh*32 + row)*8 + e2;
            unsigned short* p0 = hTw + ub;
            asm volatile("global_store_short %0, %1, off sc0 sc1"
                         :: "v"(p0), "v"((unsigned)hi) : "memory");
        }
        asm volatile("s_waitcnt vmcnt(0)" ::: "memory");   // hT drained (out not yet issued)
        __syncthreads();                                   // all waves drained

        // ---- publish EARLY, then pre-stage next W, then out-stores ----
        if (k < KSTEPS - 1) {
            if (tid == 0) {
                const unsigned kk = (unsigned)(k + 1);
                unsigned int* fp = bar + (bx * 64 + by);
                asm volatile("global_store_dword %0, %1, off sc0 sc1"
                             :: "v"(fp), "v"(kk) : "memory");
            }
            stageW(wsrc1, 0); MEMFENCE;
            stageW(wsrc1, 1); MEMFENCE;
        }

        // loop B: out stores (nontemporal; drain overlaps next cohort wait)
        #pragma unroll
        for (int it = 0; it < 4; ++it) {
            const int qi = it * 512 + tid;
            const int jl = qi & 15;
            const int m  = qi >> 4;
            const long mg = m0 + m;
            const long j  = (long)by * 16 + jl;
            __builtin_nontemporal_store(hp[it], &outk[mg * KH + j]);
        }
    }
}

// ---------------------------------------------------------------------------
extern "C" void kernel_launch(void* const* d_in, const int* in_sizes, int n_in,
                              void* d_out, int out_size, void* d_ws, size_t ws_size,
                              hipStream_t stream)
{
    const float* c   = (const float*)d_in[0];
    // d_in[1] = K (fixed 96)
    const float* wih = (const float*)d_in[2];
    const float* whh = (const float*)d_in[3];
    const float* bih = (const float*)d_in[4];
    const float* bhh = (const float*)d_in[5];
    float* out = (float*)d_out;

    unsigned short* blob0 = (unsigned short*)d_ws;            // 8.39M ushort
    unsigned short* blob1 = blob0 + 8388608L;
    float*          bcJ   = (float*)(blob1 + 8388608L);       // 4096 f32
    unsigned short* hTa   = (unsigned short*)(bcJ + 4096);    // 1M ushort
    unsigned short* hTb   = hTa + 1048576L;
    unsigned int*   bar   = (unsigned int*)(hTb + 1048576L);  // 512 u32

    prep_w  <<<dim3(32768, 2), 256, 0, stream>>>(wih, whh, blob0, blob1);
    prep_bcJ<<<dim3(16),       256, 0, stream>>>(bih, bhh, bcJ, bar);
    prep_h0 <<<dim3(2048),     256, 0, stream>>>(c, hTa);

    void* args[] = { (void*)&blob0, (void*)&blob1, (void*)&hTa, (void*)&hTb,
                     (void*)&c, (void*)&bcJ, (void*)&out, (void*)&bar };
    hipLaunchCooperativeKernel((const void*)gru_all, dim3(256), dim3(512),
                               args, 0, stream);
}

// Round 20
// 834.099 us; speedup vs baseline: 1.6684x; 1.0494x over previous
//
#include <hip/hip_runtime.h>
#include <math.h>

#define H 1024
#define BATCH 512
#define KSTEPS 96
#define KH ((long)KSTEPS * H)

typedef __attribute__((ext_vector_type(8))) short short8;
typedef __attribute__((ext_vector_type(16))) float f32x16;

__device__ __forceinline__ unsigned short f2bf(float x) {
    union { float f; unsigned int u; } v; v.f = x;
    unsigned int r = v.u + 0x7fffu + ((v.u >> 16) & 1u);
    return (unsigned short)(r >> 16);
}

// fast saturating gate math (v_exp_f32; NaN-free at +-inf)
__device__ __forceinline__ float fsig(float x)  { return 1.f / (1.f + __expf(-x)); }
__device__ __forceinline__ float ftanh(float x) { return 1.f - 2.f / (1.f + __expf(2.f * x)); }

#define MEMFENCE asm volatile("" ::: "memory")

// ---------------------------------------------------------------------------
// r20 layouts (32x32x16 MFMA fragment order, hi-only bf16):
//  blob0/blob1: [32 tc][32 Jt][4 js][2 kg][64 l][8 e]  (8 MB each)
//     J = Jt*128 + js*32 + (l&31); g = J&3; j = J>>2
//     k = tc*32 + kg*16 + (l>>5)*8 + e
//  hTa/hTb: [8 mt][2 ph][16 cc][2 mh][2 kg][64 l][8 e]  (1 MB each)
//     m = mt*64 + mh*32 + (l&31); k = (ph*16+cc)*32 + kg*16 + (l>>5)*8 + e
//     -> per (mt,ph) region is 64 KB CONTIGUOUS (A-stage identity copy)
//  bcJ: [4096] f32 J-interleaved fused biases
//  bar: [512] u32 — flag[mt*32 + Jt]: steps globally visible by that block
// ---------------------------------------------------------------------------

__global__ void prep_w(const float* __restrict__ wih,
                       const float* __restrict__ whh,
                       unsigned short* __restrict__ blob0,
                       unsigned short* __restrict__ blob1)
{
    const unsigned int f = blockIdx.x * 256 + threadIdx.x;  // 0..4194303
    const int e  = f & 7;
    const int l  = (f >> 3) & 63;
    const int kg = (f >> 9) & 1;
    const int js = (f >> 10) & 3;
    const int Jt = (f >> 12) & 31;
    const int tc = (f >> 17) & 31;
    const int b  = blockIdx.y;      // blob select

    const int J = Jt * 128 + js * 32 + (l & 31);
    const int g = J & 3;
    const long j = J >> 2;
    const long k = (long)tc * 32 + kg * 16 + (l >> 5) * 8 + e;

    float v = 0.f;
    if (b == 1) {
        if (g == 0)      v = wih[j*1024 + k]           + whh[j*1024 + k];
        else if (g == 1) v = wih[(1024+j)*1024 + k]    + whh[(1024+j)*1024 + k];
        else if (g == 2) v = wih[(2048+j)*1024 + k];
        else             v = whh[(2048+j)*1024 + k];
    } else {
        if (g == 0)      v = whh[j*1024 + k];
        else if (g == 1) v = whh[(1024+j)*1024 + k];
        else if (g == 2) v = 0.f;
        else             v = whh[(2048+j)*1024 + k];
    }
    unsigned short* blob = (b == 0) ? blob0 : blob1;
    blob[f] = f2bf(v);
}

__global__ void prep_bcJ(const float* __restrict__ bih,
                         const float* __restrict__ bhh,
                         float* __restrict__ bcJ,
                         unsigned int* __restrict__ bar)
{
    const int J = blockIdx.x * 256 + threadIdx.x;   // 0..4095
    const int g = J & 3;
    const int j = J >> 2;
    float v;
    if (g == 0)      v = bih[j]        + bhh[j];
    else if (g == 1) v = bih[1024 + j] + bhh[1024 + j];
    else if (g == 2) v = bih[2048 + j];
    else             v = bhh[2048 + j];
    bcJ[J] = v;
    if (blockIdx.x == 0) {                 // zero flag state (512 u32)
        bar[threadIdx.x]       = 0u;
        bar[256 + threadIdx.x] = 0u;
    }
}

// c [512][1024] fp32 -> hT fragment layout (hi-only)
__global__ void prep_h0(const float* __restrict__ cin,
                        unsigned short* __restrict__ hT)
{
    const unsigned int f = blockIdx.x * 256 + threadIdx.x;   // 0..524287
    const int e  = f & 7;
    const int l  = (f >> 3) & 63;
    const int kg = (f >> 9) & 1;
    const int mh = (f >> 10) & 1;
    const int cc = (f >> 11) & 15;
    const int ph = (f >> 15) & 1;
    const int mt = (f >> 16) & 7;

    const long m = mt * 64 + mh * 32 + (l & 31);
    const long k = (long)(ph * 16 + cc) * 32 + kg * 16 + (l >> 5) * 8 + e;

    hT[f] = f2bf(cin[m * 1024 + k]);
}

// ---------------------------------------------------------------------------
// Persistent GRU: all 96 steps in ONE cooperative launch.
// Grid 256 (1/CU), 512 threads (8 waves = 2 mh x 4 js).
// Block tile 64 m x 128 J. Wave = 32 m x 32 J x FULL K (no split-K).
// Pure-bf16 1-product (r19-proven). 2 MFMA/chunk/wave, 32 chunks.
// A staged per K-half into 64 KB LDS (shared by all waves, identity copy,
// sc0sc1 system-scope loads). W streamed to regs, 3-deep, plain cached
// (L2-resident per XCD), counted vmcnt, NO per-chunk barriers.
// Epilogue wave-local (private D pane + lgkmcnt, no cross-wave reduce).
// Dataflow sync: flag[mt*32+Jt]; consumers wait on 32 producers of their mt.
// ---------------------------------------------------------------------------
__global__ __launch_bounds__(512) void gru_all(
    const unsigned short* __restrict__ blob0,
    const unsigned short* __restrict__ blob1,
    unsigned short* __restrict__ hTa,
    unsigned short* __restrict__ hTb,
    const float* __restrict__ cin,
    const float* __restrict__ bcJ,
    float* __restrict__ out,
    unsigned int* bar)
{
    __shared__ __attribute__((aligned(16))) char smem[65536 + 8*4608]; // A 64KB + 8 D panes

    const int tid  = threadIdx.x;
    const int lane = tid & 63;
    const int wv   = tid >> 6;        // 0..7
    const int mh   = wv & 1;          // m-half (32 rows)
    const int js   = wv >> 1;         // J-sub (32 J)

    const int id   = blockIdx.x;
    const int grp  = id & 7;          // XCD
    const int slot = id >> 3;         // 0..31
    const int Jt   = grp * 4 + (slot & 3);   // 0..31 (J tile, XCD-local)
    const int mt   = slot >> 2;              // 0..7  (m tile)

    const float bias = bcJ[Jt * 128 + js * 32 + (lane & 31)];

    // thread's 4 outputs: m_loc = q*8 + (lane>>3) in wave tile; jj = lane&7
    const int jj   = lane & 7;
    const long jgl = (long)Jt * 32 + js * 8 + jj;       // hidden j
    float hp[4];
    #pragma unroll
    for (int q = 0; q < 4; ++q) {
        const long mg = (long)mt * 64 + mh * 32 + q * 8 + (lane >> 3);
        hp[q] = cin[mg * 1024 + jgl];
    }

    char* ldsA = smem;
    float* Dw  = (float*)(smem + 65536 + wv * 4608);    // [32][36] f32, wave-private

    #pragma unroll 1
    for (int k = 0; k < KSTEPS; ++k) {
        const unsigned short* blob = (k == 0) ? blob0 : blob1;
        const char* wbase = (const char*)blob + (long)(Jt * 8 + js * 2) * 1024; // + c*262144 (+kg*1024)
        const unsigned short* hTr = (k & 1) ? hTb : hTa;
        unsigned short*       hTw = (k & 1) ? hTa : hTb;
        const char* hbase = (const char*)hTr + (long)mt * 131072;               // + ph*65536
        float* outk = out + (long)k * H;

        short8 W0[2], W1[2], W2[2];   // 3 rotating W sets (named, static idx)

        auto loadW = [&](int c, short8* Wd) {
            const char* p = wbase + (long)c * 262144;
            asm volatile("global_load_dwordx4 %0, %1, off"
                         : "=v"(Wd[0]) : "v"(p + lane * 16) : "memory");
            asm volatile("global_load_dwordx4 %0, %1, off"
                         : "=v"(Wd[1]) : "v"(p + 1024 + lane * 16) : "memory");
        };
        // stage one 64KB K-half of A: identity copy global->LDS (8x16B/thread)
        auto stageA = [&](int ph) {
            const char* src = hbase + ph * 65536;
            short8 t0, t1, t2, t3, t4, t5, t6, t7;
            asm volatile("global_load_dwordx4 %0, %1, off sc0 sc1" : "=v"(t0) : "v"(src + (0*512 + tid)*16) : "memory");
            asm volatile("global_load_dwordx4 %0, %1, off sc0 sc1" : "=v"(t1) : "v"(src + (1*512 + tid)*16) : "memory");
            asm volatile("global_load_dwordx4 %0, %1, off sc0 sc1" : "=v"(t2) : "v"(src + (2*512 + tid)*16) : "memory");
            asm volatile("global_load_dwordx4 %0, %1, off sc0 sc1" : "=v"(t3) : "v"(src + (3*512 + tid)*16) : "memory");
            asm volatile("global_load_dwordx4 %0, %1, off sc0 sc1" : "=v"(t4) : "v"(src + (4*512 + tid)*16) : "memory");
            asm volatile("global_load_dwordx4 %0, %1, off sc0 sc1" : "=v"(t5) : "v"(src + (5*512 + tid)*16) : "memory");
            asm volatile("global_load_dwordx4 %0, %1, off sc0 sc1" : "=v"(t6) : "v"(src + (6*512 + tid)*16) : "memory");
            asm volatile("global_load_dwordx4 %0, %1, off sc0 sc1" : "=v"(t7) : "v"(src + (7*512 + tid)*16) : "memory");
            asm volatile("s_waitcnt vmcnt(0)" ::: "memory");
            __builtin_amdgcn_sched_barrier(0);
            *(short8*)(ldsA + (0*512 + tid)*16) = t0;
            *(short8*)(ldsA + (1*512 + tid)*16) = t1;
            *(short8*)(ldsA + (2*512 + tid)*16) = t2;
            *(short8*)(ldsA + (3*512 + tid)*16) = t3;
            *(short8*)(ldsA + (4*512 + tid)*16) = t4;
            *(short8*)(ldsA + (5*512 + tid)*16) = t5;
            *(short8*)(ldsA + (6*512 + tid)*16) = t6;
            *(short8*)(ldsA + (7*512 + tid)*16) = t7;
        };

        // accumulators: 2 independent chains (kg0 / kg1), bias in chain 0
        f32x16 acc0, acc1;
        #pragma unroll
        for (int r = 0; r < 16; ++r) { acc0[r] = bias; acc1[r] = 0.f; }

        // ---- W prefetch issued BEFORE the cohort wait (h-independent) ----
        loadW(0, W0); loadW(1, W1); loadW(2, W2);
        MEMFENCE;

        // ---- cohort wait: the 32 producers of our mt-slice ----
        if (k > 0) {
            if (wv == 0 && lane < 32) {
                unsigned int* fp = bar + (mt * 32 + lane);
                while (true) {
                    unsigned v;
                    asm volatile("global_load_dword %0, %1, off sc0 sc1\n\t"
                                 "s_waitcnt vmcnt(0)"
                                 : "=v"(v) : "v"(fp) : "memory");
                    if (v >= (unsigned)k) break;
                    __builtin_amdgcn_s_sleep(2);
                }
            }
        }
        __syncthreads();   // release + A/D LDS reuse safe

        // ---- A phase 0 stage ----
        stageA(0);
        __syncthreads();   // A half 0 visible to all waves

        // chunk c: wait W(c) landed (counted), 2 ds_read A, 2 MFMA, issue W(c+3)
        #define CHUNK(c, N, Wc, Wn)                                            \
        {                                                                      \
            asm volatile("s_waitcnt vmcnt(" #N ")" ::: "memory");              \
            __builtin_amdgcn_sched_barrier(0);                                 \
            const int cc_ = (c) & 15;                                          \
            const short8 a0_ = *(const short8*)(ldsA + ((cc_*2 + mh)*2 + 0)*1024 + lane*16); \
            const short8 a1_ = *(const short8*)(ldsA + ((cc_*2 + mh)*2 + 1)*1024 + lane*16); \
            acc0 = __builtin_amdgcn_mfma_f32_32x32x16_bf16(a0_, Wc[0], acc0, 0, 0, 0); \
            acc1 = __builtin_amdgcn_mfma_f32_32x32x16_bf16(a1_, Wc[1], acc1, 0, 0, 0); \
            if ((c) + 3 < 32) loadW((c) + 3, Wn);                              \
        }

        CHUNK(0,4,W0,W0)  CHUNK(1,4,W1,W1)  CHUNK(2,4,W2,W2)  CHUNK(3,4,W0,W0)
        CHUNK(4,4,W1,W1)  CHUNK(5,4,W2,W2)  CHUNK(6,4,W0,W0)  CHUNK(7,4,W1,W1)
        CHUNK(8,4,W2,W2)  CHUNK(9,4,W0,W0)  CHUNK(10,4,W1,W1) CHUNK(11,4,W2,W2)
        CHUNK(12,4,W0,W0) CHUNK(13,4,W1,W1) CHUNK(14,4,W2,W2) CHUNK(15,4,W0,W0)

        // ---- phase boundary: restage A half 1 ----
        __syncthreads();   // all waves done reading A half 0 (drains vmcnt too)
        stageA(1);
        __syncthreads();   // A half 1 visible

        CHUNK(16,4,W1,W1) CHUNK(17,4,W2,W2) CHUNK(18,4,W0,W0) CHUNK(19,4,W1,W1)
        CHUNK(20,4,W2,W2) CHUNK(21,4,W0,W0) CHUNK(22,4,W1,W1) CHUNK(23,4,W2,W2)
        CHUNK(24,4,W0,W0) CHUNK(25,4,W1,W1) CHUNK(26,4,W2,W2) CHUNK(27,4,W0,W0)
        CHUNK(28,4,W1,W1) CHUNK(29,4,W2,W2) CHUNK(30,2,W0,W0) CHUNK(31,0,W1,W1)
        #undef CHUNK

        // ---- wave-local epilogue ----
        #pragma unroll
        for (int r = 0; r < 16; ++r) {
            const int r32 = (r & 3) + 8 * (r >> 2) + 4 * (lane >> 5);
            Dw[r32 * 36 + (lane & 31)] = acc0[r] + acc1[r];
        }
        asm volatile("s_waitcnt lgkmcnt(0)" ::: "memory");
        __builtin_amdgcn_sched_barrier(0);

        #pragma unroll
        for (int q = 0; q < 4; ++q) {
            const int m_loc = q * 8 + (lane >> 3);
            const float4 gv = *(const float4*)(Dw + m_loc * 36 + jj * 4);
            const float rr = fsig(gv.x);
            const float zz = fsig(gv.y);
            const float nn = ftanh(fmaf(rr, gv.w, gv.z));
            const float o  = nn + zz * (hp[q] - nn);
            hp[q] = o;

            // hT writeback (new layout) — sc0 sc1 write-through
            const unsigned short hi = f2bf(o);
            const int j   = (int)jgl;
            const int c2  = j >> 5;
            const int kg2 = (j >> 4) & 1;
            const int lhi = (j >> 3) & 1;
            const int e2  = j & 7;
            const int ph2 = c2 >> 4;
            const int cc2 = c2 & 15;
            const int l2  = lhi * 32 + m_loc;
            const long ub = (((((long)mt*2 + ph2)*16 + cc2)*2 + mh)*2 + kg2)*512
                          + l2*8 + e2;
            unsigned short* p0 = hTw + ub;
            asm volatile("global_store_short %0, %1, off sc0 sc1"
                         :: "v"(p0), "v"((unsigned)hi) : "memory");
        }
        asm volatile("s_waitcnt vmcnt(0)" ::: "memory");   // hT drained
        __syncthreads();                                   // all waves drained

        // publish, then out-stores (drain overlaps next cohort wait)
        if (k < KSTEPS - 1 && tid == 0) {
            const unsigned kk = (unsigned)(k + 1);
            unsigned int* fp = bar + (mt * 32 + Jt);
            asm volatile("global_store_dword %0, %1, off sc0 sc1"
                         :: "v"(fp), "v"(kk) : "memory");
        }
        #pragma unroll
        for (int q = 0; q < 4; ++q) {
            const long mg = (long)mt * 64 + mh * 32 + q * 8 + (lane >> 3);
            __builtin_nontemporal_store(hp[q], &outk[mg * KH + jgl]);
        }
    }
}

// ---------------------------------------------------------------------------
extern "C" void kernel_launch(void* const* d_in, const int* in_sizes, int n_in,
                              void* d_out, int out_size, void* d_ws, size_t ws_size,
                              hipStream_t stream)
{
    const float* c   = (const float*)d_in[0];
    // d_in[1] = K (fixed 96)
    const float* wih = (const float*)d_in[2];
    const float* whh = (const float*)d_in[3];
    const float* bih = (const float*)d_in[4];
    const float* bhh = (const float*)d_in[5];
    float* out = (float*)d_out;

    unsigned short* blob0 = (unsigned short*)d_ws;            // 4.19M ushort (8 MB)
    unsigned short* blob1 = blob0 + 4194304L;
    float*          bcJ   = (float*)(blob1 + 4194304L);       // 4096 f32
    unsigned short* hTa   = (unsigned short*)(bcJ + 4096);    // 524288 ushort (1 MB)
    unsigned short* hTb   = hTa + 524288L;
    unsigned int*   bar   = (unsigned int*)(hTb + 524288L);   // 512 u32

    prep_w  <<<dim3(16384, 2), 256, 0, stream>>>(wih, whh, blob0, blob1);
    prep_bcJ<<<dim3(16),       256, 0, stream>>>(bih, bhh, bcJ, bar);
    prep_h0 <<<dim3(2048),     256, 0, stream>>>(c, hTa);

    void* args[] = { (void*)&blob0, (void*)&blob1, (void*)&hTa, (void*)&hTb,
                     (void*)&c, (void*)&bcJ, (void*)&out, (void*)&bar };
    hipLaunchCooperativeKernel((const void*)gru_all, dim3(256), dim3(512),
                               args, 0, stream);
}

// Round 21
// 816.260 us; speedup vs baseline: 1.7048x; 1.0219x over previous
//
#include <hip/hip_runtime.h>
#include <math.h>

#define H 1024
#define BATCH 512
#define KSTEPS 96
#define KH ((long)KSTEPS * H)

typedef __attribute__((ext_vector_type(8))) short short8;
typedef __attribute__((ext_vector_type(16))) float f32x16;

__device__ __forceinline__ unsigned short f2bf(float x) {
    union { float f; unsigned int u; } v; v.f = x;
    unsigned int r = v.u + 0x7fffu + ((v.u >> 16) & 1u);
    return (unsigned short)(r >> 16);
}

// fast saturating gate math (v_exp_f32; NaN-free at +-inf)
__device__ __forceinline__ float fsig(float x)  { return 1.f / (1.f + __expf(-x)); }
__device__ __forceinline__ float ftanh(float x) { return 1.f - 2.f / (1.f + __expf(2.f * x)); }

#define MEMFENCE asm volatile("" ::: "memory")

// ---------------------------------------------------------------------------
// r21 layouts (32x32x16 MFMA fragment order, hi-only bf16) — same as r20:
//  blob0/blob1: [32 tc][32 Jt][4 js][2 kg][64 l][8 e]  (8 MB each)
//     J = Jt*128 + js*32 + (l&31); g = J&3; j = J>>2
//     k = tc*32 + kg*16 + (l>>5)*8 + e
//  hTa/hTb: [8 mt][2 ph][16 cc][2 mh][2 kg][64 l][8 e]  (1 MB each)
//     m = mt*64 + mh*32 + (l&31); k = (ph*16+cc)*32 + kg*16 + (l>>5)*8 + e
//     -> per (mt,ph) region is 64 KB CONTIGUOUS (A-stage identity copy)
//  bcJ: [4096] f32 J-interleaved fused biases
//  bar: [512] u32 — flag[mt*32 + Jt]: steps globally visible by that block
// ---------------------------------------------------------------------------

__global__ void prep_w(const float* __restrict__ wih,
                       const float* __restrict__ whh,
                       unsigned short* __restrict__ blob0,
                       unsigned short* __restrict__ blob1)
{
    const unsigned int f = blockIdx.x * 256 + threadIdx.x;  // 0..4194303
    const int e  = f & 7;
    const int l  = (f >> 3) & 63;
    const int kg = (f >> 9) & 1;
    const int js = (f >> 10) & 3;
    const int Jt = (f >> 12) & 31;
    const int tc = (f >> 17) & 31;
    const int b  = blockIdx.y;      // blob select

    const int J = Jt * 128 + js * 32 + (l & 31);
    const int g = J & 3;
    const long j = J >> 2;
    const long k = (long)tc * 32 + kg * 16 + (l >> 5) * 8 + e;

    float v = 0.f;
    if (b == 1) {
        if (g == 0)      v = wih[j*1024 + k]           + whh[j*1024 + k];
        else if (g == 1) v = wih[(1024+j)*1024 + k]    + whh[(1024+j)*1024 + k];
        else if (g == 2) v = wih[(2048+j)*1024 + k];
        else             v = whh[(2048+j)*1024 + k];
    } else {
        if (g == 0)      v = whh[j*1024 + k];
        else if (g == 1) v = whh[(1024+j)*1024 + k];
        else if (g == 2) v = 0.f;
        else             v = whh[(2048+j)*1024 + k];
    }
    unsigned short* blob = (b == 0) ? blob0 : blob1;
    blob[f] = f2bf(v);
}

__global__ void prep_bcJ(const float* __restrict__ bih,
                         const float* __restrict__ bhh,
                         float* __restrict__ bcJ,
                         unsigned int* __restrict__ bar)
{
    const int J = blockIdx.x * 256 + threadIdx.x;   // 0..4095
    const int g = J & 3;
    const int j = J >> 2;
    float v;
    if (g == 0)      v = bih[j]        + bhh[j];
    else if (g == 1) v = bih[1024 + j] + bhh[1024 + j];
    else if (g == 2) v = bih[2048 + j];
    else             v = bhh[2048 + j];
    bcJ[J] = v;
    if (blockIdx.x == 0) {                 // zero flag state (512 u32)
        bar[threadIdx.x]       = 0u;
        bar[256 + threadIdx.x] = 0u;
    }
}

// c [512][1024] fp32 -> hT fragment layout (hi-only)
__global__ void prep_h0(const float* __restrict__ cin,
                        unsigned short* __restrict__ hT)
{
    const unsigned int f = blockIdx.x * 256 + threadIdx.x;   // 0..524287
    const int e  = f & 7;
    const int l  = (f >> 3) & 63;
    const int kg = (f >> 9) & 1;
    const int mh = (f >> 10) & 1;
    const int cc = (f >> 11) & 15;
    const int ph = (f >> 15) & 1;
    const int mt = (f >> 16) & 7;

    const long m = mt * 64 + mh * 32 + (l & 31);
    const long k = (long)(ph * 16 + cc) * 32 + kg * 16 + (l >> 5) * 8 + e;

    hT[f] = f2bf(cin[m * 1024 + k]);
}

// ---------------------------------------------------------------------------
// Persistent GRU: all 96 steps in ONE cooperative launch.
// Grid 256 (1/CU), 512 threads (8 waves = 2 kg x 4 js).
// Block tile 64 m x 128 J. Wave = 64 m x 32 J x K-HALF (kg) — every wave
// owns a DISTINCT W stream (zero W redundancy: 256 KB/block/step from L2).
// Pure-bf16 1-product. Per chunk per wave: 1 short8 W (3-deep, vmcnt(2)),
// 2 ds_read_b128 A (block-shared LDS, staged per K-half from IC), 2 MFMA.
// No per-chunk barriers. Epilogue: 2-way kg reduce via LDS panes.
// Dataflow sync: flag[mt*32+Jt]; consumers wait on 32 producers of their mt.
// ---------------------------------------------------------------------------
__global__ __launch_bounds__(512) void gru_all(
    const unsigned short* __restrict__ blob0,
    const unsigned short* __restrict__ blob1,
    unsigned short* __restrict__ hTa,
    unsigned short* __restrict__ hTb,
    const float* __restrict__ cin,
    const float* __restrict__ bcJ,
    float* __restrict__ out,
    unsigned int* bar)
{
    // A 64KB + 8 D panes of [64][36] f32 (stride 2308 floats = 9232 B, +4f skew)
    __shared__ __attribute__((aligned(16))) char smem[65536 + 8 * 9232];

    const int tid  = threadIdx.x;
    const int lane = tid & 63;
    const int wv   = tid >> 6;        // 0..7
    const int kg   = wv & 1;          // K-half
    const int js   = wv >> 1;         // J-sub (32 J)

    const int id   = blockIdx.x;
    const int grp  = id & 7;          // XCD
    const int slot = id >> 3;         // 0..31
    const int Jt   = grp * 4 + (slot & 3);   // 0..31 (J tile, XCD-local W slice)
    const int mt   = slot >> 2;              // 0..7  (m tile)

    const float bias = (kg == 0) ? bcJ[Jt * 128 + js * 32 + (lane & 31)] : 0.f;

    char*  ldsA  = smem;
    float* Dbase = (float*)(smem + 65536);
    float* Dp    = Dbase + (js * 2 + kg) * 2308;   // wave-private pane [64][36]

    // thread's 4 outputs (gate loop): qi = q*512+tid -> jl = qi&31, m = qi>>5
    float hp[4];
    #pragma unroll
    for (int q = 0; q < 4; ++q) {
        const int qi = q * 512 + tid;
        const int jl = qi & 31;
        const int m  = qi >> 5;
        hp[q] = cin[((long)mt * 64 + m) * 1024 + (long)Jt * 32 + jl];
    }

    #pragma unroll 1
    for (int k = 0; k < KSTEPS; ++k) {
        const unsigned short* blob = (k == 0) ? blob0 : blob1;
        const char* wbase = (const char*)blob + (long)(Jt * 8 + js * 2 + kg) * 1024; // + c*262144
        const unsigned short* hTr = (k & 1) ? hTb : hTa;
        unsigned short*       hTw = (k & 1) ? hTa : hTb;
        const char* hbase = (const char*)hTr + (long)mt * 131072;                    // + ph*65536
        float* outk = out + (long)k * H;

        short8 W0, W1, W2;   // 3 rotating W regs (1 KB fragment each)

        auto loadW = [&](int c, short8& Wd) {
            const char* p = wbase + (long)c * 262144;
            asm volatile("global_load_dwordx4 %0, %1, off"
                         : "=v"(Wd) : "v"(p + lane * 16) : "memory");
        };
        // stage one 64KB K-half of A (identity copy, sc0sc1 system-scope).
        // drainAll=false: A loads are OLDEST in FIFO -> vmcnt(3) drains A,
        // leaves the 3 W prefetches in flight. drainAll=true: vmcnt(0).
        auto stageA = [&](int ph, bool drainAll) {
            const char* src = hbase + ph * 65536;
            short8 t0, t1, t2, t3, t4, t5, t6, t7;
            asm volatile("global_load_dwordx4 %0, %1, off sc0 sc1" : "=v"(t0) : "v"(src + (0*512 + tid)*16) : "memory");
            asm volatile("global_load_dwordx4 %0, %1, off sc0 sc1" : "=v"(t1) : "v"(src + (1*512 + tid)*16) : "memory");
            asm volatile("global_load_dwordx4 %0, %1, off sc0 sc1" : "=v"(t2) : "v"(src + (2*512 + tid)*16) : "memory");
            asm volatile("global_load_dwordx4 %0, %1, off sc0 sc1" : "=v"(t3) : "v"(src + (3*512 + tid)*16) : "memory");
            asm volatile("global_load_dwordx4 %0, %1, off sc0 sc1" : "=v"(t4) : "v"(src + (4*512 + tid)*16) : "memory");
            asm volatile("global_load_dwordx4 %0, %1, off sc0 sc1" : "=v"(t5) : "v"(src + (5*512 + tid)*16) : "memory");
            asm volatile("global_load_dwordx4 %0, %1, off sc0 sc1" : "=v"(t6) : "v"(src + (6*512 + tid)*16) : "memory");
            asm volatile("global_load_dwordx4 %0, %1, off sc0 sc1" : "=v"(t7) : "v"(src + (7*512 + tid)*16) : "memory");
            if (drainAll) asm volatile("s_waitcnt vmcnt(0)" ::: "memory");
            else          asm volatile("s_waitcnt vmcnt(3)" ::: "memory");
            __builtin_amdgcn_sched_barrier(0);
            *(short8*)(ldsA + (0*512 + tid)*16) = t0;
            *(short8*)(ldsA + (1*512 + tid)*16) = t1;
            *(short8*)(ldsA + (2*512 + tid)*16) = t2;
            *(short8*)(ldsA + (3*512 + tid)*16) = t3;
            *(short8*)(ldsA + (4*512 + tid)*16) = t4;
            *(short8*)(ldsA + (5*512 + tid)*16) = t5;
            *(short8*)(ldsA + (6*512 + tid)*16) = t6;
            *(short8*)(ldsA + (7*512 + tid)*16) = t7;
            asm volatile("s_waitcnt lgkmcnt(0)" ::: "memory");
        };

        // accumulators: m-low / m-high 32x32 tiles (independent chains)
        f32x16 accLo, accHi;
        #pragma unroll
        for (int r = 0; r < 16; ++r) { accLo[r] = bias; accHi[r] = 0.f; }
        // NOTE: bias must appear once per (m,J): put it in kg0's accLo AND
        // kg0's accHi (both m-halves need it).
        if (kg == 0) {
            #pragma unroll
            for (int r = 0; r < 16; ++r) accHi[r] = bias;
        }

        // ---- cohort wait: the 32 producers of our mt-slice ----
        if (k > 0) {
            if (wv == 0 && lane < 32) {
                unsigned int* fp = bar + (mt * 32 + lane);
                while (true) {
                    unsigned v;
                    asm volatile("global_load_dword %0, %1, off sc0 sc1\n\t"
                                 "s_waitcnt vmcnt(0)"
                                 : "=v"(v) : "v"(fp) : "memory");
                    if (v >= (unsigned)k) break;
                    __builtin_amdgcn_s_sleep(2);
                }
            }
        }
        __syncthreads();   // release; h(k-1) visible; LDS reuse safe

        // ---- phase 0: stage A (issue first => A oldest), W prefetch under it ----
        {
            const char* src = hbase;   // ph=0
            // A issue happens inside stageA; W issued after so A drains first
        }
        // Issue A loads, then W0-2, then drain A only (vmcnt(3)).
        // stageA() as written issues A then we call loadW before its waitcnt —
        // inline the ordering explicitly:
        {
            // A loads (oldest)
            // reuse stageA with a twist: issue W prefetch between loads and wait
            const char* src = hbase;
            short8 t0, t1, t2, t3, t4, t5, t6, t7;
            asm volatile("global_load_dwordx4 %0, %1, off sc0 sc1" : "=v"(t0) : "v"(src + (0*512 + tid)*16) : "memory");
            asm volatile("global_load_dwordx4 %0, %1, off sc0 sc1" : "=v"(t1) : "v"(src + (1*512 + tid)*16) : "memory");
            asm volatile("global_load_dwordx4 %0, %1, off sc0 sc1" : "=v"(t2) : "v"(src + (2*512 + tid)*16) : "memory");
            asm volatile("global_load_dwordx4 %0, %1, off sc0 sc1" : "=v"(t3) : "v"(src + (3*512 + tid)*16) : "memory");
            asm volatile("global_load_dwordx4 %0, %1, off sc0 sc1" : "=v"(t4) : "v"(src + (4*512 + tid)*16) : "memory");
            asm volatile("global_load_dwordx4 %0, %1, off sc0 sc1" : "=v"(t5) : "v"(src + (5*512 + tid)*16) : "memory");
            asm volatile("global_load_dwordx4 %0, %1, off sc0 sc1" : "=v"(t6) : "v"(src + (6*512 + tid)*16) : "memory");
            asm volatile("global_load_dwordx4 %0, %1, off sc0 sc1" : "=v"(t7) : "v"(src + (7*512 + tid)*16) : "memory");
            loadW(0, W0); loadW(1, W1); loadW(2, W2);
            asm volatile("s_waitcnt vmcnt(3)" ::: "memory");   // A drained; W0-2 flying
            __builtin_amdgcn_sched_barrier(0);
            *(short8*)(ldsA + (0*512 + tid)*16) = t0;
            *(short8*)(ldsA + (1*512 + tid)*16) = t1;
            *(short8*)(ldsA + (2*512 + tid)*16) = t2;
            *(short8*)(ldsA + (3*512 + tid)*16) = t3;
            *(short8*)(ldsA + (4*512 + tid)*16) = t4;
            *(short8*)(ldsA + (5*512 + tid)*16) = t5;
            *(short8*)(ldsA + (6*512 + tid)*16) = t6;
            *(short8*)(ldsA + (7*512 + tid)*16) = t7;
            asm volatile("s_waitcnt lgkmcnt(0)" ::: "memory");
        }
        __builtin_amdgcn_s_barrier();   // A half 0 visible to all waves

        // chunk c: vmcnt(N) [W(c) landed], 2 ds_read A, 2 MFMA, issue W(c+3)
        #define CHUNK(c, N, Wc, Wn)                                            \
        {                                                                      \
            asm volatile("s_waitcnt vmcnt(" #N ")" ::: "memory");              \
            __builtin_amdgcn_sched_barrier(0);                                 \
            const short8 aLo = *(const short8*)(ldsA + (((c)&15)*4 + kg)*1024 + lane*16);     \
            const short8 aHi = *(const short8*)(ldsA + (((c)&15)*4 + 2 + kg)*1024 + lane*16); \
            accLo = __builtin_amdgcn_mfma_f32_32x32x16_bf16(aLo, Wc, accLo, 0, 0, 0); \
            accHi = __builtin_amdgcn_mfma_f32_32x32x16_bf16(aHi, Wc, accHi, 0, 0, 0); \
            if ((c) + 3 < 32) loadW((c) + 3, Wn);                              \
        }

        CHUNK(0,2,W0,W0)  CHUNK(1,2,W1,W1)  CHUNK(2,2,W2,W2)  CHUNK(3,2,W0,W0)
        CHUNK(4,2,W1,W1)  CHUNK(5,2,W2,W2)  CHUNK(6,2,W0,W0)  CHUNK(7,2,W1,W1)
        CHUNK(8,2,W2,W2)  CHUNK(9,2,W0,W0)  CHUNK(10,2,W1,W1) CHUNK(11,2,W2,W2)
        CHUNK(12,2,W0,W0) CHUNK(13,2,W1,W1) CHUNK(14,2,W2,W2) CHUNK(15,2,W0,W0)

        // ---- phase boundary: all waves done reading A half 0 ----
        __builtin_amdgcn_s_barrier();
        stageA(1, /*drainAll=*/true);    // vmcnt(0): also drains W16-18 (L2-fast)
        __builtin_amdgcn_s_barrier();    // A half 1 visible

        CHUNK(16,2,W1,W1) CHUNK(17,2,W2,W2) CHUNK(18,2,W0,W0) CHUNK(19,2,W1,W1)
        CHUNK(20,2,W2,W2) CHUNK(21,2,W0,W0) CHUNK(22,2,W1,W1) CHUNK(23,2,W2,W2)
        CHUNK(24,2,W0,W0) CHUNK(25,2,W1,W1) CHUNK(26,2,W2,W2) CHUNK(27,2,W0,W0)
        CHUNK(28,2,W1,W1) CHUNK(29,2,W2,W2) CHUNK(30,1,W0,W0) CHUNK(31,0,W1,W1)
        #undef CHUNK

        // ---- epilogue: dump both acc tiles to wave pane, 2-way kg reduce ----
        #pragma unroll
        for (int r = 0; r < 16; ++r) {
            const int r32 = (r & 3) + 8 * (r >> 2) + 4 * (lane >> 5);
            Dp[(r32)      * 36 + (lane & 31)] = accLo[r];
            Dp[(32 + r32) * 36 + (lane & 31)] = accHi[r];
        }
        asm volatile("s_waitcnt lgkmcnt(0)" ::: "memory");
        __builtin_amdgcn_s_barrier();

        #pragma unroll
        for (int q = 0; q < 4; ++q) {
            const int qi = q * 512 + tid;
            const int jl = qi & 31;        // local j-out 0..31
            const int m  = qi >> 5;        // 0..63
            const int jsq = jl >> 3;
            const int c4  = (jl & 7) * 4;
            const float4 g0 = *(const float4*)(Dbase + (jsq*2 + 0)*2308 + m*36 + c4);
            const float4 g1 = *(const float4*)(Dbase + (jsq*2 + 1)*2308 + m*36 + c4);
            const float gr = g0.x + g1.x;
            const float gz = g0.y + g1.y;
            const float gi = g0.z + g1.z;
            const float gh = g0.w + g1.w;

            const float rr = fsig(gr);
            const float zz = fsig(gz);
            const float nn = ftanh(fmaf(rr, gh, gi));
            const float o  = nn + zz * (hp[q] - nn);
            hp[q] = o;

            // hT writeback — sc0 sc1 write-through
            const unsigned short hi = f2bf(o);
            const int j   = Jt * 32 + jl;
            const int c2  = j >> 5;
            const int kg2 = (j >> 4) & 1;
            const int lhi = (j >> 3) & 1;
            const int e2  = j & 7;
            const int ph2 = c2 >> 4;
            const int cc2 = c2 & 15;
            const int mh2 = m >> 5;
            const int l2  = lhi * 32 + (m & 31);
            const long ub = (((((long)mt*2 + ph2)*16 + cc2)*2 + mh2)*2 + kg2)*512
                          + l2*8 + e2;
            unsigned short* p0 = hTw + ub;
            asm volatile("global_store_short %0, %1, off sc0 sc1"
                         :: "v"(p0), "v"((unsigned)hi) : "memory");
        }
        asm volatile("s_waitcnt vmcnt(0)" ::: "memory");   // hT drained
        __builtin_amdgcn_s_barrier();                      // all waves drained

        // publish, then out-stores (drain overlaps next cohort wait)
        if (k < KSTEPS - 1 && tid == 0) {
            const unsigned kk = (unsigned)(k + 1);
            unsigned int* fp = bar + (mt * 32 + Jt);
            asm volatile("global_store_dword %0, %1, off sc0 sc1"
                         :: "v"(fp), "v"(kk) : "memory");
        }
        #pragma unroll
        for (int q = 0; q < 4; ++q) {
            const int qi = q * 512 + tid;
            const int jl = qi & 31;
            const int m  = qi >> 5;
            __builtin_nontemporal_store(hp[q],
                &outk[((long)mt * 64 + m) * KH + (long)Jt * 32 + jl]);
        }
    }
}

// ---------------------------------------------------------------------------
extern "C" void kernel_launch(void* const* d_in, const int* in_sizes, int n_in,
                              void* d_out, int out_size, void* d_ws, size_t ws_size,
                              hipStream_t stream)
{
    const float* c   = (const float*)d_in[0];
    // d_in[1] = K (fixed 96)
    const float* wih = (const float*)d_in[2];
    const float* whh = (const float*)d_in[3];
    const float* bih = (const float*)d_in[4];
    const float* bhh = (const float*)d_in[5];
    float* out = (float*)d_out;

    unsigned short* blob0 = (unsigned short*)d_ws;            // 4.19M ushort (8 MB)
    unsigned short* blob1 = blob0 + 4194304L;
    float*          bcJ   = (float*)(blob1 + 4194304L);       // 4096 f32
    unsigned short* hTa   = (unsigned short*)(bcJ + 4096);    // 524288 ushort (1 MB)
    unsigned short* hTb   = hTa + 524288L;
    unsigned int*   bar   = (unsigned int*)(hTb + 524288L);   // 512 u32

    prep_w  <<<dim3(16384, 2), 256, 0, stream>>>(wih, whh, blob0, blob1);
    prep_bcJ<<<dim3(16),       256, 0, stream>>>(bih, bhh, bcJ, bar);
    prep_h0 <<<dim3(2048),     256, 0, stream>>>(c, hTa);

    void* args[] = { (void*)&blob0, (void*)&blob1, (void*)&hTa, (void*)&hTb,
                     (void*)&c, (void*)&bcJ, (void*)&out, (void*)&bar };
    hipLaunchCooperativeKernel((const void*)gru_all, dim3(256), dim3(512),
                               args, 0, stream);
}

// Round 22
// 799.767 us; speedup vs baseline: 1.7400x; 1.0206x over previous
//
#include <hip/hip_runtime.h>
#include <math.h>

#define H 1024
#define BATCH 512
#define KSTEPS 96
#define KH ((long)KSTEPS * H)

typedef __attribute__((ext_vector_type(8))) short short8;
typedef __attribute__((ext_vector_type(16))) float f32x16;

__device__ __forceinline__ unsigned short f2bf(float x) {
    union { float f; unsigned int u; } v; v.f = x;
    unsigned int r = v.u + 0x7fffu + ((v.u >> 16) & 1u);
    return (unsigned short)(r >> 16);
}

// fast saturating gate math (v_exp_f32; NaN-free at +-inf)
__device__ __forceinline__ float fsig(float x)  { return 1.f / (1.f + __expf(-x)); }
__device__ __forceinline__ float ftanh(float x) { return 1.f - 2.f / (1.f + __expf(2.f * x)); }

// async global->LDS 16B/lane; dst wave-uniform base (HW adds lane*16)
__device__ __forceinline__ void glds16(const void* g, void* l) {
    __builtin_amdgcn_global_load_lds(
        (const __attribute__((address_space(1))) void*)g,
        (__attribute__((address_space(3))) void*)l, 16, 0, 0);
}
#define MEMFENCE asm volatile("" ::: "memory")

// ---------------------------------------------------------------------------
// r22 layouts (identical to r21):
//  blob0/blob1: [32 tc][32 Jt][4 js][2 kg][64 l][8 e]  (8 MB each, hi-only)
//  hTa/hTb: [8 mt][2 ph][16 cc][2 mh][2 kg][64 l][8 e]  (1 MB each)
//     -> per (mt, quarter qq=c>>3) region is 32 KB CONTIGUOUS
//  bcJ: [4096] f32 J-interleaved fused biases
//  bar: [512] u32 — flag[mt*32 + Jt]
// ---------------------------------------------------------------------------

__global__ void prep_w(const float* __restrict__ wih,
                       const float* __restrict__ whh,
                       unsigned short* __restrict__ blob0,
                       unsigned short* __restrict__ blob1)
{
    const unsigned int f = blockIdx.x * 256 + threadIdx.x;  // 0..4194303
    const int e  = f & 7;
    const int l  = (f >> 3) & 63;
    const int kg = (f >> 9) & 1;
    const int js = (f >> 10) & 3;
    const int Jt = (f >> 12) & 31;
    const int tc = (f >> 17) & 31;
    const int b  = blockIdx.y;      // blob select

    const int J = Jt * 128 + js * 32 + (l & 31);
    const int g = J & 3;
    const long j = J >> 2;
    const long k = (long)tc * 32 + kg * 16 + (l >> 5) * 8 + e;

    float v = 0.f;
    if (b == 1) {
        if (g == 0)      v = wih[j*1024 + k]           + whh[j*1024 + k];
        else if (g == 1) v = wih[(1024+j)*1024 + k]    + whh[(1024+j)*1024 + k];
        else if (g == 2) v = wih[(2048+j)*1024 + k];
        else             v = whh[(2048+j)*1024 + k];
    } else {
        if (g == 0)      v = whh[j*1024 + k];
        else if (g == 1) v = whh[(1024+j)*1024 + k];
        else if (g == 2) v = 0.f;
        else             v = whh[(2048+j)*1024 + k];
    }
    unsigned short* blob = (b == 0) ? blob0 : blob1;
    blob[f] = f2bf(v);
}

__global__ void prep_bcJ(const float* __restrict__ bih,
                         const float* __restrict__ bhh,
                         float* __restrict__ bcJ,
                         unsigned int* __restrict__ bar)
{
    const int J = blockIdx.x * 256 + threadIdx.x;   // 0..4095
    const int g = J & 3;
    const int j = J >> 2;
    float v;
    if (g == 0)      v = bih[j]        + bhh[j];
    else if (g == 1) v = bih[1024 + j] + bhh[1024 + j];
    else if (g == 2) v = bih[2048 + j];
    else             v = bhh[2048 + j];
    bcJ[J] = v;
    if (blockIdx.x == 0) {                 // zero flag state (512 u32)
        bar[threadIdx.x]       = 0u;
        bar[256 + threadIdx.x] = 0u;
    }
}

// c [512][1024] fp32 -> hT fragment layout (hi-only)
__global__ void prep_h0(const float* __restrict__ cin,
                        unsigned short* __restrict__ hT)
{
    const unsigned int f = blockIdx.x * 256 + threadIdx.x;   // 0..524287
    const int e  = f & 7;
    const int l  = (f >> 3) & 63;
    const int kg = (f >> 9) & 1;
    const int mh = (f >> 10) & 1;
    const int cc = (f >> 11) & 15;
    const int ph = (f >> 15) & 1;
    const int mt = (f >> 16) & 7;

    const long m = mt * 64 + mh * 32 + (l & 31);
    const long k = (long)(ph * 16 + cc) * 32 + kg * 16 + (l >> 5) * 8 + e;

    hT[f] = f2bf(cin[m * 1024 + k]);
}

// ---------------------------------------------------------------------------
// Persistent GRU: all 96 steps in ONE cooperative launch.
// Grid 256 (1/CU), 512 threads (8 waves = 2 kg x 4 js).
// Block tile 64 m x 128 J; wave = 64 m x 32 J x K-half (distinct W streams).
// Pure-bf16 1-product (r19-proven numerics; absmax 0.015625).
// r22: A staged in FOUR 32 KB QUARTERS, double-buffered — quarter q+1 issued
//   (4 glds16/wave) inside chunk 8q, drained by chunk 8q+4's vmcnt(2)
//   (~800 cy cover), visible after the quarter-boundary s_barrier.
//   Only quarter 0 is a serial wait (true h dependency). vmcnt per chunk
//   derived entry-by-entry (see macro call list).
// Dataflow sync: flag[mt*32+Jt]; consumers wait on 32 producers of their mt.
// Coherence: hT sc0 sc1 write-through / system-scope reads; out nontemporal.
// ---------------------------------------------------------------------------
__global__ __launch_bounds__(512) void gru_all(
    const unsigned short* __restrict__ blob0,
    const unsigned short* __restrict__ blob1,
    unsigned short* __restrict__ hTa,
    unsigned short* __restrict__ hTb,
    const float* __restrict__ cin,
    const float* __restrict__ bcJ,
    float* __restrict__ out,
    unsigned int* bar)
{
    // A: 2 x 32 KB quarter buffers; D panes: 8 x [64][36] f32 (stride 2308 f)
    __shared__ __attribute__((aligned(16))) char smem[65536 + 8 * 9232];

    const int tid  = threadIdx.x;
    const int lane = tid & 63;
    const int wv   = tid >> 6;        // 0..7
    const int kg   = wv & 1;          // K-half
    const int js   = wv >> 1;         // J-sub (32 J)

    const int id   = blockIdx.x;
    const int grp  = id & 7;          // XCD
    const int slot = id >> 3;         // 0..31
    const int Jt   = grp * 4 + (slot & 3);   // 0..31 (J tile)
    const int mt   = slot >> 2;              // 0..7  (m tile)

    const float bias = (kg == 0) ? bcJ[Jt * 128 + js * 32 + (lane & 31)] : 0.f;

    char*  ldsA  = smem;
    float* Dbase = (float*)(smem + 65536);
    float* Dp    = Dbase + (js * 2 + kg) * 2308;   // wave-private pane [64][36]

    // thread's 4 outputs: qi = q*512+tid -> jl = qi&31, m = qi>>5
    float hp[4];
    #pragma unroll
    for (int q = 0; q < 4; ++q) {
        const int qi = q * 512 + tid;
        const int jl = qi & 31;
        const int m  = qi >> 5;
        hp[q] = cin[((long)mt * 64 + m) * 1024 + (long)Jt * 32 + jl];
    }

    #pragma unroll 1
    for (int k = 0; k < KSTEPS; ++k) {
        const unsigned short* blob = (k == 0) ? blob0 : blob1;
        const char* wbase = (const char*)blob + (long)(Jt * 8 + js * 2 + kg) * 1024; // + c*262144
        const unsigned short* hTr = (k & 1) ? hTb : hTa;
        unsigned short*       hTw = (k & 1) ? hTa : hTb;
        const char* hbase = (const char*)hTr + (long)mt * 131072;  // + qq*32768
        float* outk = out + (long)k * H;

        short8 W0, W1, W2;   // 3 rotating W regs

        auto loadW = [&](int c, short8& Wd) {
            const char* p = wbase + (long)c * 262144;
            asm volatile("global_load_dwordx4 %0, %1, off"
                         : "=v"(Wd) : "v"(p + lane * 16) : "memory");
        };
        // stage quarter q (32 KB) into buffer q&1: 4 glds16/wave, wave slice 4 KB
        auto stageAq = [&](int q) {
            const char* src = hbase + (long)q * 32768 + wv * 4096;
            char* dst = ldsA + (q & 1) * 32768 + wv * 4096;
            #pragma unroll
            for (int i = 0; i < 4; ++i)
                glds16(src + i * 1024 + lane * 16, dst + i * 1024);
        };

        // accumulators: m-low / m-high 32x32 tiles (bias is 0 for kg=1)
        f32x16 accLo, accHi;
        #pragma unroll
        for (int r = 0; r < 16; ++r) { accLo[r] = bias; accHi[r] = bias; }

        // ---- W prefetch (h-independent) BEFORE the cohort wait ----
        loadW(0, W0); loadW(1, W1); loadW(2, W2);
        MEMFENCE;

        // ---- cohort wait: the 32 producers of our mt-slice ----
        if (k > 0) {
            if (wv == 0 && lane < 32) {
                unsigned int* fp = bar + (mt * 32 + lane);
                while (true) {
                    unsigned v;
                    asm volatile("global_load_dword %0, %1, off sc0 sc1\n\t"
                                 "s_waitcnt vmcnt(0)"
                                 : "=v"(v) : "v"(fp) : "memory");
                    if (v >= (unsigned)k) break;
                    __builtin_amdgcn_s_sleep(1);
                }
            }
        }
        __syncthreads();   // release; h(k-1) visible; LDS reuse safe

        // ---- quarter 0: the one unavoidable serial A wait ----
        stageAq(0);
        asm volatile("s_waitcnt vmcnt(0)" ::: "memory");   // A-q0 (and W0-2) landed
        __builtin_amdgcn_sched_barrier(0);
        __builtin_amdgcn_s_barrier();                      // q0 visible to all waves

        // chunk c: vmcnt(N) -> 2 ds_read A -> 2 MFMA -> issue W(c+3) [-> stage A(q+1)]
        #define CHUNK(c, N, Wc, Wn, STG)                                       \
        {                                                                      \
            asm volatile("s_waitcnt vmcnt(" #N ")" ::: "memory");              \
            __builtin_amdgcn_sched_barrier(0);                                 \
            const short8 aLo = *(const short8*)(ldsA + (((c)>>3)&1)*32768      \
                                 + (((c)&7)*4 + kg)*1024 + lane*16);           \
            const short8 aHi = *(const short8*)(ldsA + (((c)>>3)&1)*32768      \
                                 + (((c)&7)*4 + 2 + kg)*1024 + lane*16);       \
            accLo = __builtin_amdgcn_mfma_f32_32x32x16_bf16(aLo, Wc, accLo, 0, 0, 0); \
            accHi = __builtin_amdgcn_mfma_f32_32x32x16_bf16(aHi, Wc, accHi, 0, 0, 0); \
            if ((c) + 3 < 32) loadW((c) + 3, Wn);                              \
            if (STG) stageAq(((c) >> 3) + 1);                                  \
            MEMFENCE;                                                          \
        }

        // vmcnt trace (FIFO per wave; W0-2 pre-drained by prologue vmcnt(0)):
        //  c0: out={} -> 0 (instant). c0 issues W3 then A1x4.
        //  c1: out=[W3,A1x4]=5, want nothing -> 6 (instant)
        //  c2: out=[W3,A1x4,W4]=6 -> 6 (instant)
        //  c3: out=[W3,A1x4,W4,W5]=7, want W3 -> 6
        //  c4: out=[A1x4,W4,W5,W6]=7, want W4 (drains A1) -> 2
        //  c5-c7: out=[W(c),W(c+1),W(c+2)] -> 2        [barrier]
        //  c8: -> 2; issues W11 + A2. c9-11: -> 6. c12: -> 2 (drains A2).
        //  c13-15: -> 2 [barrier] c16: -> 2; W19+A3. c17-19: -> 6. c20: -> 2.
        //  c21-23: -> 2 [barrier] c24-29: -> 2 (no stage). c30: -> 1. c31: -> 0.
        CHUNK(0,0,W0,W0,1)  CHUNK(1,6,W1,W1,0)  CHUNK(2,6,W2,W2,0)  CHUNK(3,6,W0,W0,0)
        CHUNK(4,2,W1,W1,0)  CHUNK(5,2,W2,W2,0)  CHUNK(6,2,W0,W0,0)  CHUNK(7,2,W1,W1,0)
        __builtin_amdgcn_s_barrier();   // quarter 1 visible
        CHUNK(8,2,W2,W2,1)  CHUNK(9,6,W0,W0,0)  CHUNK(10,6,W1,W1,0) CHUNK(11,6,W2,W2,0)
        CHUNK(12,2,W0,W0,0) CHUNK(13,2,W1,W1,0) CHUNK(14,2,W2,W2,0) CHUNK(15,2,W0,W0,0)
        __builtin_amdgcn_s_barrier();   // quarter 2 visible
        CHUNK(16,2,W1,W1,1) CHUNK(17,6,W2,W2,0) CHUNK(18,6,W0,W0,0) CHUNK(19,6,W1,W1,0)
        CHUNK(20,2,W2,W2,0) CHUNK(21,2,W0,W0,0) CHUNK(22,2,W1,W1,0) CHUNK(23,2,W2,W2,0)
        __builtin_amdgcn_s_barrier();   // quarter 3 visible
        CHUNK(24,2,W0,W0,0) CHUNK(25,2,W1,W1,0) CHUNK(26,2,W2,W2,0) CHUNK(27,2,W0,W0,0)
        CHUNK(28,2,W1,W1,0) CHUNK(29,2,W2,W2,0) CHUNK(30,1,W0,W0,0) CHUNK(31,0,W1,W1,0)
        #undef CHUNK

        // ---- epilogue: dump both acc tiles to wave pane, 2-way kg reduce ----
        #pragma unroll
        for (int r = 0; r < 16; ++r) {
            const int r32 = (r & 3) + 8 * (r >> 2) + 4 * (lane >> 5);
            Dp[(r32)      * 36 + (lane & 31)] = accLo[r];
            Dp[(32 + r32) * 36 + (lane & 31)] = accHi[r];
        }
        asm volatile("s_waitcnt lgkmcnt(0)" ::: "memory");
        __builtin_amdgcn_s_barrier();

        #pragma unroll
        for (int q = 0; q < 4; ++q) {
            const int qi = q * 512 + tid;
            const int jl = qi & 31;        // local j-out 0..31
            const int m  = qi >> 5;        // 0..63
            const int jsq = jl >> 3;
            const int c4  = (jl & 7) * 4;
            const float4 g0 = *(const float4*)(Dbase + (jsq*2 + 0)*2308 + m*36 + c4);
            const float4 g1 = *(const float4*)(Dbase + (jsq*2 + 1)*2308 + m*36 + c4);
            const float gr = g0.x + g1.x;
            const float gz = g0.y + g1.y;
            const float gi = g0.z + g1.z;
            const float gh = g0.w + g1.w;

            const float rr = fsig(gr);
            const float zz = fsig(gz);
            const float nn = ftanh(fmaf(rr, gh, gi));
            const float o  = nn + zz * (hp[q] - nn);
            hp[q] = o;

            // hT writeback — sc0 sc1 write-through
            const unsigned short hi = f2bf(o);
            const int j   = Jt * 32 + jl;
            const int c2  = j >> 5;
            const int kg2 = (j >> 4) & 1;
            const int lhi = (j >> 3) & 1;
            const int e2  = j & 7;
            const int ph2 = c2 >> 4;
            const int cc2 = c2 & 15;
            const int mh2 = m >> 5;
            const int l2  = lhi * 32 + (m & 31);
            const long ub = (((((long)mt*2 + ph2)*16 + cc2)*2 + mh2)*2 + kg2)*512
                          + l2*8 + e2;
            unsigned short* p0 = hTw + ub;
            asm volatile("global_store_short %0, %1, off sc0 sc1"
                         :: "v"(p0), "v"((unsigned)hi) : "memory");
        }
        asm volatile("s_waitcnt vmcnt(0)" ::: "memory");   // hT drained
        __builtin_amdgcn_s_barrier();                      // all waves drained

        // publish, then out-stores (drain overlaps next cohort wait)
        if (k < KSTEPS - 1 && tid == 0) {
            const unsigned kk = (unsigned)(k + 1);
            unsigned int* fp = bar + (mt * 32 + Jt);
            asm volatile("global_store_dword %0, %1, off sc0 sc1"
                         :: "v"(fp), "v"(kk) : "memory");
        }
        #pragma unroll
        for (int q = 0; q < 4; ++q) {
            const int qi = q * 512 + tid;
            const int jl = qi & 31;
            const int m  = qi >> 5;
            __builtin_nontemporal_store(hp[q],
                &outk[((long)mt * 64 + m) * KH + (long)Jt * 32 + jl]);
        }
    }
}

// ---------------------------------------------------------------------------
extern "C" void kernel_launch(void* const* d_in, const int* in_sizes, int n_in,
                              void* d_out, int out_size, void* d_ws, size_t ws_size,
                              hipStream_t stream)
{
    const float* c   = (const float*)d_in[0];
    // d_in[1] = K (fixed 96)
    const float* wih = (const float*)d_in[2];
    const float* whh = (const float*)d_in[3];
    const float* bih = (const float*)d_in[4];
    const float* bhh = (const float*)d_in[5];
    float* out = (float*)d_out;

    unsigned short* blob0 = (unsigned short*)d_ws;            // 4.19M ushort (8 MB)
    unsigned short* blob1 = blob0 + 4194304L;
    float*          bcJ   = (float*)(blob1 + 4194304L);       // 4096 f32
    unsigned short* hTa   = (unsigned short*)(bcJ + 4096);    // 524288 ushort (1 MB)
    unsigned short* hTb   = hTa + 524288L;
    unsigned int*   bar   = (unsigned int*)(hTb + 524288L);   // 512 u32

    prep_w  <<<dim3(16384, 2), 256, 0, stream>>>(wih, whh, blob0, blob1);
    prep_bcJ<<<dim3(16),       256, 0, stream>>>(bih, bhh, bcJ, bar);
    prep_h0 <<<dim3(2048),     256, 0, stream>>>(c, hTa);

    void* args[] = { (void*)&blob0, (void*)&blob1, (void*)&hTa, (void*)&hTb,
                     (void*)&c, (void*)&bcJ, (void*)&out, (void*)&bar };
    hipLaunchCooperativeKernel((const void*)gru_all, dim3(256), dim3(512),
                               args, 0, stream);
}